// Round 11
// baseline (199.831 us; speedup 1.0000x reference)
//
#include <hip/hip_runtime.h>
#include <hip/hip_bf16.h>

// Shapes (fixed for this problem)
#define S_LEN 2048
#define HIDDIM 2048
#define NH 16
#define NKV 4
#define HD 128
#define KVROW 1024   // KVb row = [K(512) | V(512)]
#define QKVN 3072    // fused projection width

typedef __attribute__((ext_vector_type(8))) short short8;
typedef __attribute__((ext_vector_type(8))) unsigned short ushort8;
typedef __attribute__((ext_vector_type(4))) unsigned short ushort4v;
typedef __attribute__((ext_vector_type(4))) float f32x4;

__device__ __forceinline__ unsigned short f2bf(float f) {
  union { float f; unsigned int u; } v; v.f = f;
  unsigned int r = (v.u + 0x7FFFu + ((v.u >> 16) & 1u)) >> 16;
  return (unsigned short)r;
}
__device__ __forceinline__ float bf2f(unsigned short h) {
  union { unsigned int u; float f; } v; v.u = ((unsigned int)h) << 16;
  return v.f;
}

// Async global->LDS 16B copy. dst must be wave-uniform (HW adds lane*16B);
// src is per-lane. Drained by the s_waitcnt vmcnt(0) in __syncthreads().
__device__ __forceinline__ void gl2lds16(const unsigned short* src,
                                         unsigned short* dst) {
  __builtin_amdgcn_global_load_lds(
      (const __attribute__((address_space(1))) unsigned int*)src,
      (__attribute__((address_space(3))) unsigned int*)dst, 16, 0, 0);
}

// ---------------------------------------------------------------------------
// hidden fp32 -> bf16 (vectorized 8/thread)
// ---------------------------------------------------------------------------
__global__ __launch_bounds__(256) void h2b_kernel(const float* __restrict__ H,
                                                  unsigned short* __restrict__ Hb) {
  int i = (blockIdx.x * 256 + threadIdx.x) * 8;
  float4 a = *(const float4*)(H + i), b = *(const float4*)(H + i + 4);
  ushort8 r;
  r[0] = f2bf(a.x); r[1] = f2bf(a.y); r[2] = f2bf(a.z); r[3] = f2bf(a.w);
  r[4] = f2bf(b.x); r[5] = f2bf(b.y); r[6] = f2bf(b.z); r[7] = f2bf(b.w);
  *(ushort8*)(Hb + i) = r;
}

// ---------------------------------------------------------------------------
// Weight transpose: W[k][n] fp32 (row stride Nsrc) -> Wt[n_off+n][k] bf16.
// ---------------------------------------------------------------------------
__global__ __launch_bounds__(256) void transpose_w(
    const float* __restrict__ W, unsigned short* __restrict__ Wt,
    int Nsrc, int Kdst, int n_off) {
  __shared__ unsigned short Ts[64][72];
  const int n0 = blockIdx.x * 64, k0 = blockIdx.y * 64;
  const int tid = threadIdx.x;
  const int c2 = (tid & 31) * 2, rb = tid >> 5;
#pragma unroll
  for (int p = 0; p < 8; ++p) {
    int r = rb + p * 8;
    float2 v = *(const float2*)&W[(size_t)(k0 + r) * Nsrc + n0 + c2];
    Ts[c2][r] = f2bf(v.x);
    Ts[c2 + 1][r] = f2bf(v.y);
  }
  __syncthreads();
  const int n = tid >> 2, kq = (tid & 3) * 16;
  ushort8 w0 = *(const ushort8*)&Ts[n][kq];
  ushort8 w1 = *(const ushort8*)&Ts[n][kq + 8];
  size_t base = (size_t)(n_off + n0 + n) * Kdst + k0 + kq;
  *(ushort8*)&Wt[base] = w0;
  *(ushort8*)&Wt[base + 8] = w1;
}

// ---------------------------------------------------------------------------
// V transpose: KVb[s][512+c] (bf16) -> Vt[c][s] (bf16), c<512, s<2048.
// ---------------------------------------------------------------------------
__global__ __launch_bounds__(256) void transpose_v(
    const unsigned short* __restrict__ KVb, unsigned short* __restrict__ Vt) {
  __shared__ unsigned short Ts[64][72];
  const int c0 = blockIdx.x * 64, s0 = blockIdx.y * 64;
  const int tid = threadIdx.x;
  const int sr = tid >> 2, cq = (tid & 3) * 16;
  ushort8 a = *(const ushort8*)&KVb[(size_t)(s0 + sr) * KVROW + 512 + c0 + cq];
  ushort8 b = *(const ushort8*)&KVb[(size_t)(s0 + sr) * KVROW + 512 + c0 + cq + 8];
#pragma unroll
  for (int j = 0; j < 8; ++j) { Ts[cq + j][sr] = a[j]; Ts[cq + 8 + j][sr] = b[j]; }
  __syncthreads();
  const int c = tid >> 2, sq = (tid & 3) * 16;
  ushort8 w0 = *(const ushort8*)&Ts[c][sq];
  ushort8 w1 = *(const ushort8*)&Ts[c][sq + 8];
  *(ushort8*)&Vt[(size_t)(c0 + c) * S_LEN + s0 + sq] = w0;
  *(ushort8*)&Vt[(size_t)(c0 + c) * S_LEN + s0 + sq + 8] = w1;
}

// ---------------------------------------------------------------------------
// MFMA GEMM (TN), m97 structure: C = A[M,K] @ Bt[N,K]^T, bf16 in.
// Tile 128x128, BK=32, 4 waves each computing 64x64 (4x4 frags).
// Staging via global_load_lds (async, no reg round-trip), LDS double-buffer,
// ONE barrier per K-step. CF: C fp32 (ld1) else bf16 split Qb/KVb.
// ---------------------------------------------------------------------------
template <bool CF>
__global__ __launch_bounds__(256) void gemm_tn(
    const unsigned short* __restrict__ A, const unsigned short* __restrict__ Bt,
    void* __restrict__ C1, void* __restrict__ C2,
    int M, int N, int K, int splitcol, int ld1, int ld2) {
  __shared__ unsigned short As[2][128 * 32];
  __shared__ unsigned short Bs[2][128 * 32];
  const int m0 = blockIdx.y * 128, n0 = blockIdx.x * 128;
  const int tid = threadIdx.x, wid = tid >> 6, lane = tid & 63;
  const int wr = wid >> 1, wc = wid & 1;
  const int lr = lane & 15, lg = lane >> 4;

  f32x4 acc[4][4];
#pragma unroll
  for (int m = 0; m < 4; ++m)
#pragma unroll
    for (int n = 0; n < 4; ++n) acc[m][n] = (f32x4){0.f, 0.f, 0.f, 0.f};

  // Each wave stages 2 chunks of A and 2 of B per step (1KB per call).
  const int srow0 = (wid * 2) * 16 + (lane >> 2);      // chunk j adds 16
  const int scol = (lane & 3) * 8;
  auto stage = [&](int k0, int b) {
#pragma unroll
    for (int j = 0; j < 2; ++j) {
      gl2lds16(A + (size_t)(m0 + srow0 + j * 16) * K + k0 + scol,
               &As[b][(wid * 2 + j) * 512]);
      gl2lds16(Bt + (size_t)(n0 + srow0 + j * 16) * K + k0 + scol,
               &Bs[b][(wid * 2 + j) * 512]);
    }
  };

  stage(0, 0);
  int cur = 0;
  for (int k0 = 0; k0 < K; k0 += 32) {
    __syncthreads();  // drains async stage into buf[cur]
    if (k0 + 32 < K) stage(k0 + 32, cur ^ 1);
    short8 af[4], bfv[4];
#pragma unroll
    for (int m = 0; m < 4; ++m)
      af[m] = *(const short8*)&As[cur][(wr * 64 + m * 16 + lr) * 32 + lg * 8];
#pragma unroll
    for (int n = 0; n < 4; ++n)
      bfv[n] = *(const short8*)&Bs[cur][(wc * 64 + n * 16 + lr) * 32 + lg * 8];
#pragma unroll
    for (int m = 0; m < 4; ++m)
#pragma unroll
      for (int n = 0; n < 4; ++n)
        acc[m][n] = __builtin_amdgcn_mfma_f32_16x16x32_bf16(af[m], bfv[n], acc[m][n], 0, 0, 0);
    cur ^= 1;
  }

#pragma unroll
  for (int m = 0; m < 4; ++m)
#pragma unroll
    for (int n = 0; n < 4; ++n)
#pragma unroll
      for (int r = 0; r < 4; ++r) {
        int row = m0 + wr * 64 + m * 16 + lg * 4 + r;
        int col = n0 + wc * 64 + n * 16 + lr;
        float v = acc[m][n][r];
        if (CF) ((float*)C1)[(size_t)row * ld1 + col] = v;
        else if (col < splitcol) ((unsigned short*)C1)[(size_t)row * ld1 + col] = f2bf(v);
        else ((unsigned short*)C2)[(size_t)row * ld2 + (col - splitcol)] = f2bf(v);
      }
}

// ---------------------------------------------------------------------------
// RoPE: one thread per (s, j), trig once, applied to 16 Q + 4 K heads.
// ---------------------------------------------------------------------------
__global__ void rope2(unsigned short* __restrict__ Q,
                      unsigned short* __restrict__ KV,
                      const int* __restrict__ pos) {
  int idx = blockIdx.x * blockDim.x + threadIdx.x;
  if (idx >= S_LEN * 64) return;
  int s = idx >> 6, j = idx & 63;
  float inv = exp2f(-0.2076205059304703f * (float)j);  // 10000^(-j/64)
  float ang = (float)pos[s] * inv;
  float sn, cs;
  __sincosf(ang, &sn, &cs);
  auto rot = [&](unsigned short* base) {
    unsigned* p = (unsigned*)base;
    unsigned v = *p;
    float x0 = bf2f((unsigned short)(v & 0xffff));
    float x1 = bf2f((unsigned short)(v >> 16));
    unsigned r = (unsigned)f2bf(x0 * cs - x1 * sn) |
                 ((unsigned)f2bf(x0 * sn + x1 * cs) << 16);
    *p = r;
  };
#pragma unroll
  for (int hh = 0; hh < NH; ++hh) rot(Q + (size_t)s * HIDDIM + hh * HD + 2 * j);
#pragma unroll
  for (int hh = 0; hh < NKV; ++hh) rot(KV + (size_t)s * KVROW + hh * HD + 2 * j);
}

// ---------------------------------------------------------------------------
// Compact attention_mask [S] int32 -> bitmask words (1 bit per key).
// ---------------------------------------------------------------------------
__global__ void maskbits_kernel(const int* __restrict__ amask,
                                unsigned* __restrict__ mb) {
  int w = threadIdx.x;  // 64 words
  unsigned m = 0;
#pragma unroll
  for (int b = 0; b < 32; ++b) m |= (amask[w * 32 + b] != 0 ? 1u : 0u) << b;
  mb[w] = m;
}

// ---------------------------------------------------------------------------
// Flash attention v10: R9 GQA-shared 8-wave block + global_load_lds staging.
// Block = (32 q-rows x kv-group), 512 thr = 4 heads x 2 row-groups.
// K tile [32][128] UNPADDED, XOR-swizzled via pre-swizzled global source
// (rule #21: linear dest + inverse-swz source + swz read): byte ^= (row&7)<<4.
// V^T tile [128][32] linear (even bank spread). One barrier/tile, LDS dbuf.
// Swapped QK^T, static-max softmax, Plds P-path, setprio on MFMA.
// ---------------------------------------------------------------------------
__global__ __launch_bounds__(512) void attn_kernel(
    const unsigned short* __restrict__ Qb, const unsigned short* __restrict__ KVb,
    const unsigned short* __restrict__ VtG, const unsigned* __restrict__ mbits,
    unsigned short* __restrict__ Ob) {
  __shared__ unsigned short Klds[2][32 * 128];  // K[key][d], swizzled
  __shared__ unsigned short Vlds[2][128 * 32];  // V^T[d][key], linear
  __shared__ unsigned short Plds[8][16][40];    // per-wave P[q][key]
  const int kvh = blockIdx.y;
  const int qt = 63 - (int)blockIdx.x;  // LPT: longest first
  const int qb = qt * 32;
  const int tid = threadIdx.x, wid = tid >> 6, lane = tid & 63;
  const int lr = lane & 15, lg = lane >> 4;
  const int h = kvh * 4 + (wid & 3);    // this wave's head
  const int rg = wid >> 2;              // row-group 0/1
  const int qrow0 = qb + rg * 16;

  short8 qf[4];
  {
    const unsigned short* qp = Qb + (size_t)(qrow0 + lr) * HIDDIM + h * HD;
#pragma unroll
    for (int c = 0; c < 4; ++c) qf[c] = *(const short8*)(qp + c * 32 + lg * 8);
  }
  f32x4 o[8];
#pragma unroll
  for (int c = 0; c < 8; ++c) o[c] = (f32x4){0.f, 0.f, 0.f, 0.f};
  float lsum = 0.f;

  const unsigned short* Vg = VtG + (size_t)(kvh * HD) * S_LEN;

  // K stage: wave w covers rows 4w..4w+3 (1KB). Source col pre-swizzled.
  const int ksrow = (wid << 2) + (lane >> 4);           // 0..31
  const int kslin = (lane & 15) << 4;                   // linear byte in row
  const int kssrc = kslin ^ ((ksrow & 7) << 4);         // swizzled source byte
  // V stage: wave w covers d-rows 16w..16w+15 (1KB), linear.
  const int vsd = (wid << 4) + (lane >> 2);
  const int vsc = (lane & 3) << 3;

  auto stage = [&](int kt, int b) {
    gl2lds16(KVb + (size_t)(kt + ksrow) * KVROW + kvh * HD + (kssrc >> 1),
             &Klds[b][0] + (size_t)wid * 512);
    gl2lds16(Vg + (size_t)vsd * S_LEN + kt + vsc,
             &Vlds[b][0] + (size_t)wid * 512);
  };

  stage(0, 0);

  const int nk = qb + 32;
  const int qr = qrow0 + lr;  // this lane's q-row
  const float SCALE = 0.08838834764831845f;
  int cur = 0;

  for (int kt = 0; kt < nk; kt += 32) {
    __syncthreads();  // drains async stage into buf[cur]
    if (kt + 32 < nk) stage(kt + 32, cur ^ 1);

    f32x4 sc[2];
    sc[0] = (f32x4){0.f, 0.f, 0.f, 0.f};
    sc[1] = (f32x4){0.f, 0.f, 0.f, 0.f};
    const char* kbase = (const char*)&Klds[cur][0];
    __builtin_amdgcn_s_setprio(1);
#pragma unroll
    for (int t = 0; t < 2; ++t)
#pragma unroll
      for (int c = 0; c < 4; ++c) {
        short8 kf = *(const short8*)(kbase + ((t * 16 + lr) << 8) +
                                     (((c << 6) + (lg << 4)) ^ ((lr & 7) << 4)));
        sc[t] = __builtin_amdgcn_mfma_f32_16x16x32_bf16(kf, qf[c], sc[t], 0, 0, 0);
      }
    __builtin_amdgcn_s_setprio(0);
    const unsigned mw = mbits[kt >> 5];
    float p[2][4];
#pragma unroll
    for (int t = 0; t < 2; ++t)
#pragma unroll
      for (int r = 0; r < 4; ++r) {
        int kk = t * 16 + lg * 4 + r;
        bool ok = (kt + kk <= qr) && ((mw >> kk) & 1u);
        float s = ok ? sc[t][r] * SCALE - 3.0f : -1e30f;
        float pv = __expf(s);
        p[t][r] = pv;
        lsum += pv;
      }
    // P -> A-frag layout via per-wave LDS (same-wave write->read)
#pragma unroll
    for (int t = 0; t < 2; ++t) {
      ushort4v pk;
#pragma unroll
      for (int r = 0; r < 4; ++r) pk[r] = f2bf(p[t][r]);
      *(ushort4v*)&Plds[wid][lr][t * 16 + lg * 4] = pk;
    }
    short8 pf = *(const short8*)&Plds[wid][lr][lg * 8];
    __builtin_amdgcn_s_setprio(1);
#pragma unroll
    for (int c = 0; c < 8; ++c) {
      short8 vf = *(const short8*)&Vlds[cur][(c * 16 + lr) * 32 + lg * 8];
      o[c] = __builtin_amdgcn_mfma_f32_16x16x32_bf16(pf, vf, o[c], 0, 0, 0);
    }
    __builtin_amdgcn_s_setprio(0);
    cur ^= 1;
  }

  // Row-sum totals: lanes {lr, lr+16, lr+32, lr+48} hold key-disjoint partials.
  float ls = lsum;
  ls += __shfl_xor(ls, 16, 64);
  ls += __shfl_xor(ls, 32, 64);
  float lrec[4];
#pragma unroll
  for (int r = 0; r < 4; ++r) lrec[r] = 1.0f / __shfl(ls, lg * 4 + r, 16);

#pragma unroll
  for (int c = 0; c < 8; ++c)
#pragma unroll
    for (int r = 0; r < 4; ++r) {
      const int row = qrow0 + lg * 4 + r;
      Ob[(size_t)row * HIDDIM + h * HD + c * 16 + lr] = f2bf(o[c][r] * lrec[r]);
    }
}

// ---------------------------------------------------------------------------
extern "C" void kernel_launch(void* const* d_in, const int* in_sizes, int n_in,
                              void* d_out, int out_size, void* d_ws, size_t ws_size,
                              hipStream_t stream) {
  const float* hidden = (const float*)d_in[0];
  const float* wq = (const float*)d_in[1];
  const float* wk = (const float*)d_in[2];
  const float* wv = (const float*)d_in[3];
  const float* wo = (const float*)d_in[4];
  const int* amask = (const int*)d_in[5];
  const int* pos = (const int*)d_in[6];

  unsigned short* Qb = (unsigned short*)d_ws;              // [2048][2048] bf16
  unsigned short* KVb = Qb + (size_t)S_LEN * HIDDIM;       // [2048][1024] K|V
  unsigned short* Ab = KVb + (size_t)S_LEN * KVROW;        // [2048][2048]
  unsigned short* WT1 = Ab + (size_t)S_LEN * HIDDIM;       // [3072][2048] Wqkv^T / Wo^T
  unsigned short* Hb = WT1 + (size_t)QKVN * HIDDIM;        // [2048][2048] bf16 hidden
  unsigned* mbits = (unsigned*)(Hb + (size_t)S_LEN * HIDDIM);
  unsigned short* Vt = WT1 + (size_t)HIDDIM * HIDDIM;      // alias Wk/WvT region,
                                                           // dead after QKV gemm
  float* out = (float*)d_out;

  dim3 blk(256);
  h2b_kernel<<<2048, blk, 0, stream>>>(hidden, Hb);
  transpose_w<<<dim3(32, 32), blk, 0, stream>>>(wq, WT1, HIDDIM, HIDDIM, 0);
  transpose_w<<<dim3(8, 32), blk, 0, stream>>>(wk, WT1, 512, HIDDIM, 2048);
  transpose_w<<<dim3(8, 32), blk, 0, stream>>>(wv, WT1, 512, HIDDIM, 2560);
  // Fused QKV projection: cols<2048 -> Qb, else -> KVb
  gemm_tn<false><<<dim3(QKVN / 128, S_LEN / 128), blk, 0, stream>>>(
      Hb, WT1, Qb, KVb, S_LEN, QKVN, HIDDIM, 2048, HIDDIM, KVROW);
  // V transpose into dead WkT/WvT region (V is not rope'd)
  transpose_v<<<dim3(8, 32), blk, 0, stream>>>(KVb, Vt);
  // Wo^T into WT1[0..2048) (Wq^T dead after QKV gemm)
  transpose_w<<<dim3(32, 32), blk, 0, stream>>>(wo, WT1, HIDDIM, HIDDIM, 0);
  rope2<<<(S_LEN * 64 + 255) / 256, blk, 0, stream>>>(Qb, KVb, pos);
  maskbits_kernel<<<1, 64, 0, stream>>>(amask, mbits);
  // Attention: block = (32 q-rows x kv-group), 8 waves
  attn_kernel<<<dim3(64, NKV), dim3(512), 0, stream>>>(Qb, KVb, Vt, mbits, Ab);
  // Output projection (fp32 out)
  gemm_tn<true><<<dim3(HIDDIM / 128, S_LEN / 128), blk, 0, stream>>>(
      Ab, WT1, out, nullptr, S_LEN, HIDDIM, HIDDIM, HIDDIM, HIDDIM, 0);
}

// Round 12
// 184.585 us; speedup vs baseline: 1.0826x; 1.0826x over previous
//
#include <hip/hip_runtime.h>
#include <hip/hip_bf16.h>

// Shapes (fixed for this problem)
#define S_LEN 2048
#define HIDDIM 2048
#define NH 16
#define NKV 4
#define HD 128
#define KVROW 1024   // KVb row = [K(512) | V(512)]
#define QKVN 3072    // fused projection width

typedef __attribute__((ext_vector_type(8))) short short8;
typedef __attribute__((ext_vector_type(8))) unsigned short ushort8;
typedef __attribute__((ext_vector_type(4))) unsigned short ushort4v;
typedef __attribute__((ext_vector_type(4))) float f32x4;

__device__ __forceinline__ unsigned short f2bf(float f) {
  union { float f; unsigned int u; } v; v.f = f;
  unsigned int r = (v.u + 0x7FFFu + ((v.u >> 16) & 1u)) >> 16;
  return (unsigned short)r;
}
__device__ __forceinline__ float bf2f(unsigned short h) {
  union { unsigned int u; float f; } v; v.u = ((unsigned int)h) << 16;
  return v.f;
}

// Async global->LDS 16B copy. dst wave-uniform (HW adds lane*16B); src per-lane.
__device__ __forceinline__ void gl2lds16(const unsigned short* src,
                                         unsigned short* dst) {
  __builtin_amdgcn_global_load_lds(
      (const __attribute__((address_space(1))) unsigned int*)src,
      (__attribute__((address_space(3))) unsigned int*)dst, 16, 0, 0);
}

// ---------------------------------------------------------------------------
__global__ __launch_bounds__(256) void h2b_kernel(const float* __restrict__ H,
                                                  unsigned short* __restrict__ Hb) {
  int i = (blockIdx.x * 256 + threadIdx.x) * 8;
  float4 a = *(const float4*)(H + i), b = *(const float4*)(H + i + 4);
  ushort8 r;
  r[0] = f2bf(a.x); r[1] = f2bf(a.y); r[2] = f2bf(a.z); r[3] = f2bf(a.w);
  r[4] = f2bf(b.x); r[5] = f2bf(b.y); r[6] = f2bf(b.z); r[7] = f2bf(b.w);
  *(ushort8*)(Hb + i) = r;
}

// ---------------------------------------------------------------------------
__global__ __launch_bounds__(256) void transpose_w(
    const float* __restrict__ W, unsigned short* __restrict__ Wt,
    int Nsrc, int Kdst, int n_off) {
  __shared__ unsigned short Ts[64][72];
  const int n0 = blockIdx.x * 64, k0 = blockIdx.y * 64;
  const int tid = threadIdx.x;
  const int c2 = (tid & 31) * 2, rb = tid >> 5;
#pragma unroll
  for (int p = 0; p < 8; ++p) {
    int r = rb + p * 8;
    float2 v = *(const float2*)&W[(size_t)(k0 + r) * Nsrc + n0 + c2];
    Ts[c2][r] = f2bf(v.x);
    Ts[c2 + 1][r] = f2bf(v.y);
  }
  __syncthreads();
  const int n = tid >> 2, kq = (tid & 3) * 16;
  ushort8 w0 = *(const ushort8*)&Ts[n][kq];
  ushort8 w1 = *(const ushort8*)&Ts[n][kq + 8];
  size_t base = (size_t)(n_off + n0 + n) * Kdst + k0 + kq;
  *(ushort8*)&Wt[base] = w0;
  *(ushort8*)&Wt[base + 8] = w1;
}

// ---------------------------------------------------------------------------
__global__ __launch_bounds__(256) void transpose_v(
    const unsigned short* __restrict__ KVb, unsigned short* __restrict__ Vt) {
  __shared__ unsigned short Ts[64][72];
  const int c0 = blockIdx.x * 64, s0 = blockIdx.y * 64;
  const int tid = threadIdx.x;
  const int sr = tid >> 2, cq = (tid & 3) * 16;
  ushort8 a = *(const ushort8*)&KVb[(size_t)(s0 + sr) * KVROW + 512 + c0 + cq];
  ushort8 b = *(const ushort8*)&KVb[(size_t)(s0 + sr) * KVROW + 512 + c0 + cq + 8];
#pragma unroll
  for (int j = 0; j < 8; ++j) { Ts[cq + j][sr] = a[j]; Ts[cq + 8 + j][sr] = b[j]; }
  __syncthreads();
  const int c = tid >> 2, sq = (tid & 3) * 16;
  ushort8 w0 = *(const ushort8*)&Ts[c][sq];
  ushort8 w1 = *(const ushort8*)&Ts[c][sq + 8];
  *(ushort8*)&Vt[(size_t)(c0 + c) * S_LEN + s0 + sq] = w0;
  *(ushort8*)&Vt[(size_t)(c0 + c) * S_LEN + s0 + sq + 8] = w1;
}

// ---------------------------------------------------------------------------
// MFMA GEMM (TN), proven R10 version: BM=128, BN=64, BK=64, padded LDS,
// reg-prefetch staging. CF: C fp32 else bf16 split C1/C2.
// ---------------------------------------------------------------------------
template <bool CF>
__global__ __launch_bounds__(256) void gemm_tn(
    const unsigned short* __restrict__ A, const unsigned short* __restrict__ Bt,
    void* __restrict__ C1, void* __restrict__ C2,
    int M, int N, int K, int splitcol, int ld1, int ld2) {
  __shared__ unsigned short As[128][72];
  __shared__ unsigned short Bs[64][72];
  const int m0 = blockIdx.y * 128, n0 = blockIdx.x * 64;
  const int tid = threadIdx.x, wid = tid >> 6, lane = tid & 63;
  const int wr = wid >> 1, wc = wid & 1;
  const int lr = lane & 15, lg = lane >> 4;

  f32x4 acc[4][2];
#pragma unroll
  for (int m = 0; m < 4; ++m)
#pragma unroll
    for (int n = 0; n < 2; ++n) acc[m][n] = (f32x4){0.f, 0.f, 0.f, 0.f};

  const int ar = tid >> 1, ac = (tid & 1) * 32;
  const int br = tid >> 2, bc = (tid & 3) * 16;

  ushort8 areg[4], breg[2];
  auto loadA = [&](int k0) {
#pragma unroll
    for (int i = 0; i < 4; ++i)
      areg[i] = *(const ushort8*)(A + (size_t)(m0 + ar) * K + k0 + ac + i * 8);
  };
  auto loadB = [&](int k0) {
    breg[0] = *(const ushort8*)(Bt + (size_t)(n0 + br) * K + k0 + bc);
    breg[1] = *(const ushort8*)(Bt + (size_t)(n0 + br) * K + k0 + bc + 8);
  };
  auto writeS = [&]() {
#pragma unroll
    for (int i = 0; i < 4; ++i) *(ushort8*)&As[ar][ac + i * 8] = areg[i];
    *(ushort8*)&Bs[br][bc] = breg[0];
    *(ushort8*)&Bs[br][bc + 8] = breg[1];
  };

  loadA(0); loadB(0);
  writeS();

  for (int k0 = 0; k0 < K; k0 += 64) {
    __syncthreads();
    if (k0 + 64 < K) {
      loadA(k0 + 64); loadB(k0 + 64);
      asm volatile("" ::: "memory");
    }
#pragma unroll
    for (int s = 0; s < 2; ++s) {
      short8 af[4], bfv[2];
#pragma unroll
      for (int m = 0; m < 4; ++m)
        af[m] = *(const short8*)&As[wr * 64 + m * 16 + lr][s * 32 + lg * 8];
#pragma unroll
      for (int n = 0; n < 2; ++n)
        bfv[n] = *(const short8*)&Bs[wc * 32 + n * 16 + lr][s * 32 + lg * 8];
#pragma unroll
      for (int m = 0; m < 4; ++m)
#pragma unroll
        for (int n = 0; n < 2; ++n)
          acc[m][n] = __builtin_amdgcn_mfma_f32_16x16x32_bf16(af[m], bfv[n], acc[m][n], 0, 0, 0);
    }
    __syncthreads();
    if (k0 + 64 < K) writeS();
  }

#pragma unroll
  for (int m = 0; m < 4; ++m)
#pragma unroll
    for (int n = 0; n < 2; ++n)
#pragma unroll
      for (int r = 0; r < 4; ++r) {
        int row = m0 + wr * 64 + m * 16 + lg * 4 + r;
        int col = n0 + wc * 32 + n * 16 + lr;
        float v = acc[m][n][r];
        if (CF) ((float*)C1)[(size_t)row * ld1 + col] = v;
        else if (col < splitcol) ((unsigned short*)C1)[(size_t)row * ld1 + col] = f2bf(v);
        else ((unsigned short*)C2)[(size_t)row * ld2 + (col - splitcol)] = f2bf(v);
      }
}

// ---------------------------------------------------------------------------
__global__ void rope2(unsigned short* __restrict__ Q,
                      unsigned short* __restrict__ KV,
                      const int* __restrict__ pos) {
  int idx = blockIdx.x * blockDim.x + threadIdx.x;
  if (idx >= S_LEN * 64) return;
  int s = idx >> 6, j = idx & 63;
  float inv = exp2f(-0.2076205059304703f * (float)j);
  float ang = (float)pos[s] * inv;
  float sn, cs;
  __sincosf(ang, &sn, &cs);
  auto rot = [&](unsigned short* base) {
    unsigned* p = (unsigned*)base;
    unsigned v = *p;
    float x0 = bf2f((unsigned short)(v & 0xffff));
    float x1 = bf2f((unsigned short)(v >> 16));
    unsigned r = (unsigned)f2bf(x0 * cs - x1 * sn) |
                 ((unsigned)f2bf(x0 * sn + x1 * cs) << 16);
    *p = r;
  };
#pragma unroll
  for (int hh = 0; hh < NH; ++hh) rot(Q + (size_t)s * HIDDIM + hh * HD + 2 * j);
#pragma unroll
  for (int hh = 0; hh < NKV; ++hh) rot(KV + (size_t)s * KVROW + hh * HD + 2 * j);
}

// ---------------------------------------------------------------------------
__global__ void maskbits_kernel(const int* __restrict__ amask,
                                unsigned* __restrict__ mb) {
  int w = threadIdx.x;
  unsigned m = 0;
#pragma unroll
  for (int b = 0; b < 32; ++b) m |= (amask[w * 32 + b] != 0 ? 1u : 0u) << b;
  mb[w] = m;
}

// ---------------------------------------------------------------------------
// Flash attention v11: UNIFORM-WORK CHUNKED grid. Work item = (qt, chunk c,
// kvh); chunk = 512 keys (16 tiles). nchunks(qt) = (qt>>4)+1. Grid (256,4)
// with uniform early-exit -> 640 real blocks of 8 waves, ~3 blocks/CU, all
// nearly equal length (load balance independent of dispatch placement).
// qt<16 (single chunk): direct normalized write. qt>=16: additive bf16
// partials (exact under static-max softmax) + f32 Lpart, combined later.
// Block = 8 waves = 4 heads x 2 row-groups sharing K/V (GQA). Staging via
// global_load_lds; K and V^T tiles XOR-swizzled via pre-swizzled source.
// ---------------------------------------------------------------------------
__global__ __launch_bounds__(512) void attn_kernel(
    const unsigned short* __restrict__ Qb, const unsigned short* __restrict__ KVb,
    const unsigned short* __restrict__ VtG, const unsigned* __restrict__ mbits,
    unsigned short* __restrict__ Ob,
    unsigned short* __restrict__ Opart, float* __restrict__ Lpart, int nsplit) {
  const int x = (int)blockIdx.x;        // 0..255
  const int qt = 63 - (x >> 2);         // diagonal (short) chunks last
  const int c = x & 3;
  const int kvh = (int)blockIdx.y;
  const int nch = (qt >> 4) + 1;        // = ceil((qt+1)/16)
  if (nsplit == 0) { if (c != 0) return; }
  else if (c >= nch) return;
  const int qb = qt * 32;
  int kbeg = 0, kend = qb + 32;
  bool partial = false;
  if (nsplit && nch > 1) {
    kbeg = c * 512;
    kend = min(kend, kbeg + 512);
    partial = true;
  }

  __shared__ unsigned short Klds[2][32 * 128];  // K[key][d], swizzled
  __shared__ unsigned short Vlds[2][128 * 32];  // V^T[d][key], swizzled
  __shared__ unsigned short Plds[8][16][40];    // per-wave P[q][key]
  const int tid = threadIdx.x, wid = tid >> 6, lane = tid & 63;
  const int lr = lane & 15, lg = lane >> 4;
  const int h = kvh * 4 + (wid & 3);
  const int rg = wid >> 2;
  const int qrow0 = qb + rg * 16;

  short8 qf[4];
  {
    const unsigned short* qp = Qb + (size_t)(qrow0 + lr) * HIDDIM + h * HD;
#pragma unroll
    for (int cc = 0; cc < 4; ++cc) qf[cc] = *(const short8*)(qp + cc * 32 + lg * 8);
  }
  f32x4 o[8];
#pragma unroll
  for (int cc = 0; cc < 8; ++cc) o[cc] = (f32x4){0.f, 0.f, 0.f, 0.f};
  float lsum = 0.f;

  const unsigned short* Vg = VtG + (size_t)(kvh * HD) * S_LEN;

  // K stage: wave w -> rows 4w..4w+3; source col pre-swizzled (^(row&7)<<4).
  const int ksrow = (wid << 2) + (lane >> 4);
  const int kssrc = ((lane & 15) << 4) ^ ((ksrow & 7) << 4);  // bytes
  // V stage: wave w -> d-rows 16w..16w+15; source pre-swizzled (^(row&3)<<4).
  const int vsd = (wid << 4) + (lane >> 2);
  const int vssrc = (((lane & 3) << 4) ^ ((vsd & 3) << 4));   // bytes

  auto stage = [&](int kt, int b) {
    gl2lds16(KVb + (size_t)(kt + ksrow) * KVROW + kvh * HD + (kssrc >> 1),
             &Klds[b][0] + (size_t)wid * 512);
    gl2lds16(Vg + (size_t)vsd * S_LEN + kt + (vssrc >> 1),
             &Vlds[b][0] + (size_t)wid * 512);
  };

  stage(kbeg, 0);

  const int qr = qrow0 + lr;
  const float SCALE = 0.08838834764831845f;
  int cur = 0;

  for (int kt = kbeg; kt < kend; kt += 32) {
    __syncthreads();  // drains async stage into buf[cur]
    if (kt + 32 < kend) stage(kt + 32, cur ^ 1);

    f32x4 sc[2];
    sc[0] = (f32x4){0.f, 0.f, 0.f, 0.f};
    sc[1] = (f32x4){0.f, 0.f, 0.f, 0.f};
    const unsigned short* kbase = &Klds[cur][0];
    __builtin_amdgcn_s_setprio(1);
#pragma unroll
    for (int t = 0; t < 2; ++t)
#pragma unroll
      for (int cc = 0; cc < 4; ++cc) {
        // row (t*16+lr), swizzled col shorts: ((cc*64+lg*16)^((lr&7)*16))/2
        short8 kf = *(const short8*)(kbase + ((t * 16 + lr) << 7) +
                                     ((((cc << 6) + (lg << 4)) ^ ((lr & 7) << 4)) >> 1));
        sc[t] = __builtin_amdgcn_mfma_f32_16x16x32_bf16(kf, qf[cc], sc[t], 0, 0, 0);
      }
    __builtin_amdgcn_s_setprio(0);
    const unsigned mw = mbits[kt >> 5];
    float p[2][4];
#pragma unroll
    for (int t = 0; t < 2; ++t)
#pragma unroll
      for (int r = 0; r < 4; ++r) {
        int kk = t * 16 + lg * 4 + r;
        bool ok = (kt + kk <= qr) && ((mw >> kk) & 1u);
        float s = ok ? sc[t][r] * SCALE - 3.0f : -1e30f;
        float pv = __expf(s);
        p[t][r] = pv;
        lsum += pv;
      }
#pragma unroll
    for (int t = 0; t < 2; ++t) {
      ushort4v pk;
#pragma unroll
      for (int r = 0; r < 4; ++r) pk[r] = f2bf(p[t][r]);
      *(ushort4v*)&Plds[wid][lr][t * 16 + lg * 4] = pk;
    }
    short8 pf = *(const short8*)&Plds[wid][lr][lg * 8];
    const unsigned short* vbase = &Vlds[cur][0];
    __builtin_amdgcn_s_setprio(1);
#pragma unroll
    for (int cc = 0; cc < 8; ++cc) {
      // row (cc*16+lr), swizzled col shorts: (lg^(lr&3))*8
      short8 vf = *(const short8*)(vbase + ((cc * 16 + lr) << 5) +
                                   ((lg ^ (lr & 3)) << 3));
      o[cc] = __builtin_amdgcn_mfma_f32_16x16x32_bf16(pf, vf, o[cc], 0, 0, 0);
    }
    __builtin_amdgcn_s_setprio(0);
    cur ^= 1;
  }

  float ls = lsum;
  ls += __shfl_xor(ls, 16, 64);
  ls += __shfl_xor(ls, 32, 64);

  if (!partial) {
    float lrec[4];
#pragma unroll
    for (int r = 0; r < 4; ++r) lrec[r] = 1.0f / __shfl(ls, lg * 4 + r, 16);
#pragma unroll
    for (int cc = 0; cc < 8; ++cc)
#pragma unroll
      for (int r = 0; r < 4; ++r) {
        const int row = qrow0 + lg * 4 + r;
        Ob[(size_t)row * HIDDIM + h * HD + cc * 16 + lr] = f2bf(o[cc][r] * lrec[r]);
      }
  } else {
    // slot packing: g=qt>>4 in {1,2,3}; base 0/32/80; nch=g+1
    const int g = qt >> 4, j = qt & 15;
    const int base = (g == 1) ? 0 : (g == 2) ? 32 : 80;
    const int slot = base + j * nch + c + 144 * kvh;
    if (lg == 0) Lpart[slot * 128 + (wid & 3) * 32 + rg * 16 + lr] = ls;
#pragma unroll
    for (int cc = 0; cc < 8; ++cc)
#pragma unroll
      for (int r = 0; r < 4; ++r)
        Opart[(size_t)slot * 16384 + (wid & 3) * 4096 +
              (rg * 16 + lg * 4 + r) * 128 + cc * 16 + lr] = f2bf(o[cc][r]);
  }
}

// ---------------------------------------------------------------------------
// Combine nch additive partials: o = sum(o_c) / sum(l_c). Grid (48, 4).
// ---------------------------------------------------------------------------
__global__ __launch_bounds__(256) void combine_kernel(
    const unsigned short* __restrict__ Opart, const float* __restrict__ Lpart,
    unsigned short* __restrict__ Ab) {
  const int qt = 16 + (int)blockIdx.x;
  const int kvh = (int)blockIdx.y;
  const int nch = (qt >> 4) + 1;
  const int g = qt >> 4, j = qt & 15;
  const int base = (g == 1) ? 0 : (g == 2) ? 32 : 80;
  const int s0 = base + j * nch + 144 * kvh;
  const int tid = threadIdx.x;
  const int rowid = tid >> 1;         // 0..127 = hg*32 + row32
  const int d0 = (tid & 1) * 64;
  float L = 0.f;
  for (int cc = 0; cc < nch; ++cc) L += Lpart[(s0 + cc) * 128 + rowid];
  const float linv = 1.0f / L;
  const int h = kvh * 4 + (rowid >> 5);
  const int row = qt * 32 + (rowid & 31);
  unsigned short* dst = Ab + (size_t)row * HIDDIM + h * HD + d0;
  for (int i = 0; i < 64; i += 8) {
    float acc[8] = {0, 0, 0, 0, 0, 0, 0, 0};
    for (int cc = 0; cc < nch; ++cc) {
      ushort8 v = *(const ushort8*)&Opart[(size_t)(s0 + cc) * 16384 +
                                          rowid * 128 + d0 + i];
#pragma unroll
      for (int k = 0; k < 8; ++k) acc[k] += bf2f(v[k]);
    }
    ushort8 r;
#pragma unroll
    for (int k = 0; k < 8; ++k) r[k] = f2bf(acc[k] * linv);
    *(ushort8*)(dst + i) = r;
  }
}

// ---------------------------------------------------------------------------
extern "C" void kernel_launch(void* const* d_in, const int* in_sizes, int n_in,
                              void* d_out, int out_size, void* d_ws, size_t ws_size,
                              hipStream_t stream) {
  const float* hidden = (const float*)d_in[0];
  const float* wq = (const float*)d_in[1];
  const float* wk = (const float*)d_in[2];
  const float* wv = (const float*)d_in[3];
  const float* wo = (const float*)d_in[4];
  const int* amask = (const int*)d_in[5];
  const int* pos = (const int*)d_in[6];

  unsigned short* Qb = (unsigned short*)d_ws;              // 0      .. 8.39MB
  unsigned short* KVb = Qb + (size_t)S_LEN * HIDDIM;       // 8.39   .. 12.58
  unsigned short* Ab = KVb + (size_t)S_LEN * KVROW;        // 12.58  .. 20.97
  unsigned short* WT1 = Ab + (size_t)S_LEN * HIDDIM;       // 20.97  .. 33.55
  unsigned short* Hb = WT1 + (size_t)QKVN * HIDDIM;        // 33.55  .. 41.94
  float* out = (float*)d_out;

  // Chunked-path extras (aliasing WT1+Hb, dead during attn):
  unsigned short* Opart = WT1;                             // 576 slots x 32KB
  unsigned short* Vt_chunk = WT1 + (size_t)576 * 16384;    // ends exactly at Hb end
  unsigned* mbits_chunk = (unsigned*)((char*)d_ws + 41943040ull);
  float* Lpart = (float*)((char*)d_ws + 41943296ull);
  const size_t need_chunk = 42238208ull;
  // Fallback locations (proven R9 footprint):
  unsigned short* Vt_fb = WT1 + (size_t)HIDDIM * HIDDIM;
  unsigned* mbits_fb = (unsigned*)((char*)d_ws + 31457280ull);

  const int nsplit = (ws_size >= need_chunk) ? 1 : 0;
  unsigned short* Vt = nsplit ? Vt_chunk : Vt_fb;
  unsigned* mbits = nsplit ? mbits_chunk : mbits_fb;

  dim3 blk(256);
  h2b_kernel<<<2048, blk, 0, stream>>>(hidden, Hb);
  transpose_w<<<dim3(32, 32), blk, 0, stream>>>(wq, WT1, HIDDIM, HIDDIM, 0);
  transpose_w<<<dim3(8, 32), blk, 0, stream>>>(wk, WT1, 512, HIDDIM, 2048);
  transpose_w<<<dim3(8, 32), blk, 0, stream>>>(wv, WT1, 512, HIDDIM, 2560);
  // Fused QKV projection: cols<2048 -> Qb, else -> KVb
  gemm_tn<false><<<dim3(QKVN / 64, S_LEN / 128), blk, 0, stream>>>(
      Hb, WT1, Qb, KVb, S_LEN, QKVN, HIDDIM, 2048, HIDDIM, KVROW);
  // V transpose (V not rope'd); location depends on path
  transpose_v<<<dim3(8, 32), blk, 0, stream>>>(KVb, Vt);
  rope2<<<(S_LEN * 64 + 255) / 256, blk, 0, stream>>>(Qb, KVb, pos);
  maskbits_kernel<<<1, 64, 0, stream>>>(amask, mbits);
  // Attention: uniform-work chunked grid
  attn_kernel<<<dim3(256, NKV), dim3(512), 0, stream>>>(
      Qb, KVb, Vt, mbits, Ab, Opart, Lpart, nsplit);
  if (nsplit)
    combine_kernel<<<dim3(48, NKV), blk, 0, stream>>>(Opart, Lpart, Ab);
  // Wo^T AFTER attn/combine (it overwrites the Opart region)
  transpose_w<<<dim3(32, 32), blk, 0, stream>>>(wo, WT1, HIDDIM, HIDDIM, 0);
  // Output projection (fp32 out)
  gemm_tn<true><<<dim3(HIDDIM / 64, S_LEN / 128), blk, 0, stream>>>(
      Ab, WT1, out, nullptr, S_LEN, HIDDIM, HIDDIM, HIDDIM, HIDDIM, 0);
}

// Round 13
// 171.430 us; speedup vs baseline: 1.1657x; 1.0767x over previous
//
#include <hip/hip_runtime.h>
#include <hip/hip_bf16.h>

// Shapes (fixed for this problem)
#define S_LEN 2048
#define HIDDIM 2048
#define NH 16
#define NKV 4
#define HD 128
#define KVROW 1024   // KVb row = [K(512) | V(512)]
#define QKVN 3072    // fused projection width

typedef __attribute__((ext_vector_type(8))) short short8;
typedef __attribute__((ext_vector_type(8))) unsigned short ushort8;
typedef __attribute__((ext_vector_type(4))) unsigned short ushort4v;
typedef __attribute__((ext_vector_type(4))) float f32x4;

__device__ __forceinline__ unsigned short f2bf(float f) {
  union { float f; unsigned int u; } v; v.f = f;
  unsigned int r = (v.u + 0x7FFFu + ((v.u >> 16) & 1u)) >> 16;
  return (unsigned short)r;
}
__device__ __forceinline__ float bf2f(unsigned short h) {
  union { unsigned int u; float f; } v; v.u = ((unsigned int)h) << 16;
  return v.f;
}

// Async global->LDS 16B copy. dst wave-uniform (HW adds lane*16B); src per-lane.
__device__ __forceinline__ void gl2lds16(const unsigned short* src,
                                         unsigned short* dst) {
  __builtin_amdgcn_global_load_lds(
      (const __attribute__((address_space(1))) unsigned int*)src,
      (__attribute__((address_space(3))) unsigned int*)dst, 16, 0, 0);
}

// ---------------------------------------------------------------------------
__global__ __launch_bounds__(256) void h2b_kernel(const float* __restrict__ H,
                                                  unsigned short* __restrict__ Hb) {
  int i = (blockIdx.x * 256 + threadIdx.x) * 8;
  float4 a = *(const float4*)(H + i), b = *(const float4*)(H + i + 4);
  ushort8 r;
  r[0] = f2bf(a.x); r[1] = f2bf(a.y); r[2] = f2bf(a.z); r[3] = f2bf(a.w);
  r[4] = f2bf(b.x); r[5] = f2bf(b.y); r[6] = f2bf(b.z); r[7] = f2bf(b.w);
  *(ushort8*)(Hb + i) = r;
}

// ---------------------------------------------------------------------------
__global__ __launch_bounds__(256) void transpose_w(
    const float* __restrict__ W, unsigned short* __restrict__ Wt,
    int Nsrc, int Kdst, int n_off) {
  __shared__ unsigned short Ts[64][72];
  const int n0 = blockIdx.x * 64, k0 = blockIdx.y * 64;
  const int tid = threadIdx.x;
  const int c2 = (tid & 31) * 2, rb = tid >> 5;
#pragma unroll
  for (int p = 0; p < 8; ++p) {
    int r = rb + p * 8;
    float2 v = *(const float2*)&W[(size_t)(k0 + r) * Nsrc + n0 + c2];
    Ts[c2][r] = f2bf(v.x);
    Ts[c2 + 1][r] = f2bf(v.y);
  }
  __syncthreads();
  const int n = tid >> 2, kq = (tid & 3) * 16;
  ushort8 w0 = *(const ushort8*)&Ts[n][kq];
  ushort8 w1 = *(const ushort8*)&Ts[n][kq + 8];
  size_t base = (size_t)(n_off + n0 + n) * Kdst + k0 + kq;
  *(ushort8*)&Wt[base] = w0;
  *(ushort8*)&Wt[base + 8] = w1;
}

// ---------------------------------------------------------------------------
__global__ __launch_bounds__(256) void transpose_v(
    const unsigned short* __restrict__ KVb, unsigned short* __restrict__ Vt) {
  __shared__ unsigned short Ts[64][72];
  const int c0 = blockIdx.x * 64, s0 = blockIdx.y * 64;
  const int tid = threadIdx.x;
  const int sr = tid >> 2, cq = (tid & 3) * 16;
  ushort8 a = *(const ushort8*)&KVb[(size_t)(s0 + sr) * KVROW + 512 + c0 + cq];
  ushort8 b = *(const ushort8*)&KVb[(size_t)(s0 + sr) * KVROW + 512 + c0 + cq + 8];
#pragma unroll
  for (int j = 0; j < 8; ++j) { Ts[cq + j][sr] = a[j]; Ts[cq + 8 + j][sr] = b[j]; }
  __syncthreads();
  const int c = tid >> 2, sq = (tid & 3) * 16;
  ushort8 w0 = *(const ushort8*)&Ts[c][sq];
  ushort8 w1 = *(const ushort8*)&Ts[c][sq + 8];
  *(ushort8*)&Vt[(size_t)(c0 + c) * S_LEN + s0 + sq] = w0;
  *(ushort8*)&Vt[(size_t)(c0 + c) * S_LEN + s0 + sq + 8] = w1;
}

// ---------------------------------------------------------------------------
// MFMA GEMM (TN) v3: BM=128, BN=64, BK=64, 4 waves 2x2 (wave 64x32).
// Staging via global_load_lds (6 x 16B/thread/step), LDS double-buffered,
// ONE barrier per K-step. Unpadded [row][64]-short tiles; bank conflicts
// killed by XOR swizzle (linear LDS dest + pre-swizzled global source +
// swizzled read, rule #21): colb ^= (row&7)<<4 within each 128B row.
// CF: C fp32 else bf16 split C1/C2.
// ---------------------------------------------------------------------------
template <bool CF>
__global__ __launch_bounds__(256) void gemm_tn(
    const unsigned short* __restrict__ A, const unsigned short* __restrict__ Bt,
    void* __restrict__ C1, void* __restrict__ C2,
    int M, int N, int K, int splitcol, int ld1, int ld2) {
  __shared__ unsigned short As[2][128 * 64];
  __shared__ unsigned short Bs[2][64 * 64];
  const int m0 = blockIdx.y * 128, n0 = blockIdx.x * 64;
  const int tid = threadIdx.x, wid = tid >> 6, lane = tid & 63;
  const int wr = wid >> 1, wc = wid & 1;
  const int lr = lane & 15, lg = lane >> 4;

  f32x4 acc[4][2];
#pragma unroll
  for (int m = 0; m < 4; ++m)
#pragma unroll
    for (int n = 0; n < 2; ++n) acc[m][n] = (f32x4){0.f, 0.f, 0.f, 0.f};

  // Staging: each gl2lds16 call writes 1KB (64 lanes x 16B) = 8 rows of 128B.
  const int srow = lane >> 3;          // 0..7 within the 8-row group
  const int scolb = (lane & 7) << 4;   // byte col 0..112
  auto stage = [&](int k0, int b) {
#pragma unroll
    for (int j = 0; j < 4; ++j) {      // A: wave wid rows wid*32 + j*8 ..+7
      int row = wid * 32 + j * 8 + srow;
      int src = (scolb ^ ((row & 7) << 4)) >> 1;  // pre-swizzled source (shorts)
      gl2lds16(A + (size_t)(m0 + row) * K + k0 + src,
               &As[b][(wid * 32 + j * 8) * 64]);
    }
#pragma unroll
    for (int j = 0; j < 2; ++j) {      // B: wave wid rows wid*16 + j*8 ..+7
      int row = wid * 16 + j * 8 + srow;
      int src = (scolb ^ ((row & 7) << 4)) >> 1;
      gl2lds16(Bt + (size_t)(n0 + row) * K + k0 + src,
               &Bs[b][(wid * 16 + j * 8) * 64]);
    }
  };

  stage(0, 0);
  int cur = 0;
  for (int k0 = 0; k0 < K; k0 += 64) {
    __syncthreads();  // drains async stage -> buf[cur] ready
    if (k0 + 64 < K) stage(k0 + 64, cur ^ 1);
#pragma unroll
    for (int s = 0; s < 2; ++s) {
      short8 af[4], bfv[2];
#pragma unroll
      for (int m = 0; m < 4; ++m) {
        int row = wr * 64 + m * 16 + lr;
        int off = ((s * 64 + lg * 16) ^ ((row & 7) << 4)) >> 1;  // shorts
        af[m] = *(const short8*)&As[cur][row * 64 + off];
      }
#pragma unroll
      for (int n = 0; n < 2; ++n) {
        int row = wc * 32 + n * 16 + lr;
        int off = ((s * 64 + lg * 16) ^ ((row & 7) << 4)) >> 1;
        bfv[n] = *(const short8*)&Bs[cur][row * 64 + off];
      }
#pragma unroll
      for (int m = 0; m < 4; ++m)
#pragma unroll
        for (int n = 0; n < 2; ++n)
          acc[m][n] = __builtin_amdgcn_mfma_f32_16x16x32_bf16(af[m], bfv[n], acc[m][n], 0, 0, 0);
    }
    cur ^= 1;
  }

#pragma unroll
  for (int m = 0; m < 4; ++m)
#pragma unroll
    for (int n = 0; n < 2; ++n)
#pragma unroll
      for (int r = 0; r < 4; ++r) {
        int row = m0 + wr * 64 + m * 16 + lg * 4 + r;
        int col = n0 + wc * 32 + n * 16 + lr;
        float v = acc[m][n][r];
        if (CF) ((float*)C1)[(size_t)row * ld1 + col] = v;
        else if (col < splitcol) ((unsigned short*)C1)[(size_t)row * ld1 + col] = f2bf(v);
        else ((unsigned short*)C2)[(size_t)row * ld2 + (col - splitcol)] = f2bf(v);
      }
}

// ---------------------------------------------------------------------------
__global__ void rope2(unsigned short* __restrict__ Q,
                      unsigned short* __restrict__ KV,
                      const int* __restrict__ pos) {
  int idx = blockIdx.x * blockDim.x + threadIdx.x;
  if (idx >= S_LEN * 64) return;
  int s = idx >> 6, j = idx & 63;
  float inv = exp2f(-0.2076205059304703f * (float)j);
  float ang = (float)pos[s] * inv;
  float sn, cs;
  __sincosf(ang, &sn, &cs);
  auto rot = [&](unsigned short* base) {
    unsigned* p = (unsigned*)base;
    unsigned v = *p;
    float x0 = bf2f((unsigned short)(v & 0xffff));
    float x1 = bf2f((unsigned short)(v >> 16));
    unsigned r = (unsigned)f2bf(x0 * cs - x1 * sn) |
                 ((unsigned)f2bf(x0 * sn + x1 * cs) << 16);
    *p = r;
  };
#pragma unroll
  for (int hh = 0; hh < NH; ++hh) rot(Q + (size_t)s * HIDDIM + hh * HD + 2 * j);
#pragma unroll
  for (int hh = 0; hh < NKV; ++hh) rot(KV + (size_t)s * KVROW + hh * HD + 2 * j);
}

// ---------------------------------------------------------------------------
__global__ void maskbits_kernel(const int* __restrict__ amask,
                                unsigned* __restrict__ mb) {
  int w = threadIdx.x;
  unsigned m = 0;
#pragma unroll
  for (int b = 0; b < 32; ++b) m |= (amask[w * 32 + b] != 0 ? 1u : 0u) << b;
  mb[w] = m;
}

// ---------------------------------------------------------------------------
// Flash attention v11 (unchanged from R12): uniform-work chunked grid.
// ---------------------------------------------------------------------------
__global__ __launch_bounds__(512) void attn_kernel(
    const unsigned short* __restrict__ Qb, const unsigned short* __restrict__ KVb,
    const unsigned short* __restrict__ VtG, const unsigned* __restrict__ mbits,
    unsigned short* __restrict__ Ob,
    unsigned short* __restrict__ Opart, float* __restrict__ Lpart, int nsplit) {
  const int x = (int)blockIdx.x;        // 0..255
  const int qt = 63 - (x >> 2);         // diagonal (short) chunks last
  const int c = x & 3;
  const int kvh = (int)blockIdx.y;
  const int nch = (qt >> 4) + 1;
  if (nsplit == 0) { if (c != 0) return; }
  else if (c >= nch) return;
  const int qb = qt * 32;
  int kbeg = 0, kend = qb + 32;
  bool partial = false;
  if (nsplit && nch > 1) {
    kbeg = c * 512;
    kend = min(kend, kbeg + 512);
    partial = true;
  }

  __shared__ unsigned short Klds[2][32 * 128];  // K[key][d], swizzled
  __shared__ unsigned short Vlds[2][128 * 32];  // V^T[d][key], swizzled
  __shared__ unsigned short Plds[8][16][40];    // per-wave P[q][key]
  const int tid = threadIdx.x, wid = tid >> 6, lane = tid & 63;
  const int lr = lane & 15, lg = lane >> 4;
  const int h = kvh * 4 + (wid & 3);
  const int rg = wid >> 2;
  const int qrow0 = qb + rg * 16;

  short8 qf[4];
  {
    const unsigned short* qp = Qb + (size_t)(qrow0 + lr) * HIDDIM + h * HD;
#pragma unroll
    for (int cc = 0; cc < 4; ++cc) qf[cc] = *(const short8*)(qp + cc * 32 + lg * 8);
  }
  f32x4 o[8];
#pragma unroll
  for (int cc = 0; cc < 8; ++cc) o[cc] = (f32x4){0.f, 0.f, 0.f, 0.f};
  float lsum = 0.f;

  const unsigned short* Vg = VtG + (size_t)(kvh * HD) * S_LEN;

  const int ksrow = (wid << 2) + (lane >> 4);
  const int kssrc = ((lane & 15) << 4) ^ ((ksrow & 7) << 4);  // bytes
  const int vsd = (wid << 4) + (lane >> 2);
  const int vssrc = (((lane & 3) << 4) ^ ((vsd & 3) << 4));   // bytes

  auto stage = [&](int kt, int b) {
    gl2lds16(KVb + (size_t)(kt + ksrow) * KVROW + kvh * HD + (kssrc >> 1),
             &Klds[b][0] + (size_t)wid * 512);
    gl2lds16(Vg + (size_t)vsd * S_LEN + kt + (vssrc >> 1),
             &Vlds[b][0] + (size_t)wid * 512);
  };

  stage(kbeg, 0);

  const int qr = qrow0 + lr;
  const float SCALE = 0.08838834764831845f;
  int cur = 0;

  for (int kt = kbeg; kt < kend; kt += 32) {
    __syncthreads();
    if (kt + 32 < kend) stage(kt + 32, cur ^ 1);

    f32x4 sc[2];
    sc[0] = (f32x4){0.f, 0.f, 0.f, 0.f};
    sc[1] = (f32x4){0.f, 0.f, 0.f, 0.f};
    const unsigned short* kbase = &Klds[cur][0];
    __builtin_amdgcn_s_setprio(1);
#pragma unroll
    for (int t = 0; t < 2; ++t)
#pragma unroll
      for (int cc = 0; cc < 4; ++cc) {
        short8 kf = *(const short8*)(kbase + ((t * 16 + lr) << 7) +
                                     ((((cc << 6) + (lg << 4)) ^ ((lr & 7) << 4)) >> 1));
        sc[t] = __builtin_amdgcn_mfma_f32_16x16x32_bf16(kf, qf[cc], sc[t], 0, 0, 0);
      }
    __builtin_amdgcn_s_setprio(0);
    const unsigned mw = mbits[kt >> 5];
    float p[2][4];
#pragma unroll
    for (int t = 0; t < 2; ++t)
#pragma unroll
      for (int r = 0; r < 4; ++r) {
        int kk = t * 16 + lg * 4 + r;
        bool ok = (kt + kk <= qr) && ((mw >> kk) & 1u);
        float s = ok ? sc[t][r] * SCALE - 3.0f : -1e30f;
        float pv = __expf(s);
        p[t][r] = pv;
        lsum += pv;
      }
#pragma unroll
    for (int t = 0; t < 2; ++t) {
      ushort4v pk;
#pragma unroll
      for (int r = 0; r < 4; ++r) pk[r] = f2bf(p[t][r]);
      *(ushort4v*)&Plds[wid][lr][t * 16 + lg * 4] = pk;
    }
    short8 pf = *(const short8*)&Plds[wid][lr][lg * 8];
    const unsigned short* vbase = &Vlds[cur][0];
    __builtin_amdgcn_s_setprio(1);
#pragma unroll
    for (int cc = 0; cc < 8; ++cc) {
      short8 vf = *(const short8*)(vbase + ((cc * 16 + lr) << 5) +
                                   ((lg ^ (lr & 3)) << 3));
      o[cc] = __builtin_amdgcn_mfma_f32_16x16x32_bf16(pf, vf, o[cc], 0, 0, 0);
    }
    __builtin_amdgcn_s_setprio(0);
    cur ^= 1;
  }

  float ls = lsum;
  ls += __shfl_xor(ls, 16, 64);
  ls += __shfl_xor(ls, 32, 64);

  if (!partial) {
    float lrec[4];
#pragma unroll
    for (int r = 0; r < 4; ++r) lrec[r] = 1.0f / __shfl(ls, lg * 4 + r, 16);
#pragma unroll
    for (int cc = 0; cc < 8; ++cc)
#pragma unroll
      for (int r = 0; r < 4; ++r) {
        const int row = qrow0 + lg * 4 + r;
        Ob[(size_t)row * HIDDIM + h * HD + cc * 16 + lr] = f2bf(o[cc][r] * lrec[r]);
      }
  } else {
    const int g = qt >> 4, j = qt & 15;
    const int base = (g == 1) ? 0 : (g == 2) ? 32 : 80;
    const int slot = base + j * nch + c + 144 * kvh;
    if (lg == 0) Lpart[slot * 128 + (wid & 3) * 32 + rg * 16 + lr] = ls;
#pragma unroll
    for (int cc = 0; cc < 8; ++cc)
#pragma unroll
      for (int r = 0; r < 4; ++r)
        Opart[(size_t)slot * 16384 + (wid & 3) * 4096 +
              (rg * 16 + lg * 4 + r) * 128 + cc * 16 + lr] = f2bf(o[cc][r]);
  }
}

// ---------------------------------------------------------------------------
__global__ __launch_bounds__(256) void combine_kernel(
    const unsigned short* __restrict__ Opart, const float* __restrict__ Lpart,
    unsigned short* __restrict__ Ab) {
  const int qt = 16 + (int)blockIdx.x;
  const int kvh = (int)blockIdx.y;
  const int nch = (qt >> 4) + 1;
  const int g = qt >> 4, j = qt & 15;
  const int base = (g == 1) ? 0 : (g == 2) ? 32 : 80;
  const int s0 = base + j * nch + 144 * kvh;
  const int tid = threadIdx.x;
  const int rowid = tid >> 1;
  const int d0 = (tid & 1) * 64;
  float L = 0.f;
  for (int cc = 0; cc < nch; ++cc) L += Lpart[(s0 + cc) * 128 + rowid];
  const float linv = 1.0f / L;
  const int h = kvh * 4 + (rowid >> 5);
  const int row = qt * 32 + (rowid & 31);
  unsigned short* dst = Ab + (size_t)row * HIDDIM + h * HD + d0;
  for (int i = 0; i < 64; i += 8) {
    float acc[8] = {0, 0, 0, 0, 0, 0, 0, 0};
    for (int cc = 0; cc < nch; ++cc) {
      ushort8 v = *(const ushort8*)&Opart[(size_t)(s0 + cc) * 16384 +
                                          rowid * 128 + d0 + i];
#pragma unroll
      for (int k = 0; k < 8; ++k) acc[k] += bf2f(v[k]);
    }
    ushort8 r;
#pragma unroll
    for (int k = 0; k < 8; ++k) r[k] = f2bf(acc[k] * linv);
    *(ushort8*)(dst + i) = r;
  }
}

// ---------------------------------------------------------------------------
extern "C" void kernel_launch(void* const* d_in, const int* in_sizes, int n_in,
                              void* d_out, int out_size, void* d_ws, size_t ws_size,
                              hipStream_t stream) {
  const float* hidden = (const float*)d_in[0];
  const float* wq = (const float*)d_in[1];
  const float* wk = (const float*)d_in[2];
  const float* wv = (const float*)d_in[3];
  const float* wo = (const float*)d_in[4];
  const int* amask = (const int*)d_in[5];
  const int* pos = (const int*)d_in[6];

  unsigned short* Qb = (unsigned short*)d_ws;              // 0      .. 8.39MB
  unsigned short* KVb = Qb + (size_t)S_LEN * HIDDIM;       // 8.39   .. 12.58
  unsigned short* Ab = KVb + (size_t)S_LEN * KVROW;        // 12.58  .. 20.97
  unsigned short* WT1 = Ab + (size_t)S_LEN * HIDDIM;       // 20.97  .. 33.55
  unsigned short* Hb = WT1 + (size_t)QKVN * HIDDIM;        // 33.55  .. 41.94
  float* out = (float*)d_out;

  // Chunked-path extras (aliasing WT1+Hb, dead during attn):
  unsigned short* Opart = WT1;                             // 576 slots x 32KB
  unsigned short* Vt_chunk = WT1 + (size_t)576 * 16384;
  unsigned* mbits_chunk = (unsigned*)((char*)d_ws + 41943040ull);
  float* Lpart = (float*)((char*)d_ws + 41943296ull);
  const size_t need_chunk = 42238208ull;
  // Fallback locations:
  unsigned short* Vt_fb = WT1 + (size_t)HIDDIM * HIDDIM;
  unsigned* mbits_fb = (unsigned*)((char*)d_ws + 31457280ull);

  const int nsplit = (ws_size >= need_chunk) ? 1 : 0;
  unsigned short* Vt = nsplit ? Vt_chunk : Vt_fb;
  unsigned* mbits = nsplit ? mbits_chunk : mbits_fb;

  dim3 blk(256);
  h2b_kernel<<<2048, blk, 0, stream>>>(hidden, Hb);
  transpose_w<<<dim3(32, 32), blk, 0, stream>>>(wq, WT1, HIDDIM, HIDDIM, 0);
  transpose_w<<<dim3(8, 32), blk, 0, stream>>>(wk, WT1, 512, HIDDIM, 2048);
  transpose_w<<<dim3(8, 32), blk, 0, stream>>>(wv, WT1, 512, HIDDIM, 2560);
  // Fused QKV projection: cols<2048 -> Qb, else -> KVb
  gemm_tn<false><<<dim3(QKVN / 64, S_LEN / 128), blk, 0, stream>>>(
      Hb, WT1, Qb, KVb, S_LEN, QKVN, HIDDIM, 2048, HIDDIM, KVROW);
  // V transpose (V not rope'd)
  transpose_v<<<dim3(8, 32), blk, 0, stream>>>(KVb, Vt);
  rope2<<<(S_LEN * 64 + 255) / 256, blk, 0, stream>>>(Qb, KVb, pos);
  maskbits_kernel<<<1, 64, 0, stream>>>(amask, mbits);
  // Attention: uniform-work chunked grid
  attn_kernel<<<dim3(256, NKV), dim3(512), 0, stream>>>(
      Qb, KVb, Vt, mbits, Ab, Opart, Lpart, nsplit);
  if (nsplit)
    combine_kernel<<<dim3(48, NKV), blk, 0, stream>>>(Opart, Lpart, Ab);
  // Wo^T AFTER attn/combine (it overwrites the Opart region)
  transpose_w<<<dim3(32, 32), blk, 0, stream>>>(wo, WT1, HIDDIM, HIDDIM, 0);
  // Output projection (fp32 out)
  gemm_tn<true><<<dim3(HIDDIM / 64, S_LEN / 128), blk, 0, stream>>>(
      Ab, WT1, out, nullptr, S_LEN, HIDDIM, HIDDIM, HIDDIM, HIDDIM, 0);
}

// Round 14
// 170.544 us; speedup vs baseline: 1.1717x; 1.0052x over previous
//
#include <hip/hip_runtime.h>
#include <hip/hip_bf16.h>

// Shapes (fixed for this problem)
#define S_LEN 2048
#define HIDDIM 2048
#define NH 16
#define NKV 4
#define HD 128
#define KVROW 1024   // KVb row = [K(512) | V(512)]
#define QKVN 3072    // fused projection width

typedef __attribute__((ext_vector_type(8))) short short8;
typedef __attribute__((ext_vector_type(8))) unsigned short ushort8;
typedef __attribute__((ext_vector_type(4))) unsigned short ushort4v;
typedef __attribute__((ext_vector_type(4))) float f32x4;

__device__ __forceinline__ unsigned short f2bf(float f) {
  union { float f; unsigned int u; } v; v.f = f;
  unsigned int r = (v.u + 0x7FFFu + ((v.u >> 16) & 1u)) >> 16;
  return (unsigned short)r;
}
__device__ __forceinline__ float bf2f(unsigned short h) {
  union { unsigned int u; float f; } v; v.u = ((unsigned int)h) << 16;
  return v.f;
}

// Async global->LDS 16B copy. dst wave-uniform (HW adds lane*16B); src per-lane.
__device__ __forceinline__ void gl2lds16(const unsigned short* src,
                                         unsigned short* dst) {
  __builtin_amdgcn_global_load_lds(
      (const __attribute__((address_space(1))) unsigned int*)src,
      (__attribute__((address_space(3))) unsigned int*)dst, 16, 0, 0);
}

// ---------------------------------------------------------------------------
__global__ __launch_bounds__(256) void h2b_kernel(const float* __restrict__ H,
                                                  unsigned short* __restrict__ Hb) {
  int i = (blockIdx.x * 256 + threadIdx.x) * 8;
  float4 a = *(const float4*)(H + i), b = *(const float4*)(H + i + 4);
  ushort8 r;
  r[0] = f2bf(a.x); r[1] = f2bf(a.y); r[2] = f2bf(a.z); r[3] = f2bf(a.w);
  r[4] = f2bf(b.x); r[5] = f2bf(b.y); r[6] = f2bf(b.z); r[7] = f2bf(b.w);
  *(ushort8*)(Hb + i) = r;
}

// ---------------------------------------------------------------------------
__global__ __launch_bounds__(256) void transpose_w(
    const float* __restrict__ W, unsigned short* __restrict__ Wt,
    int Nsrc, int Kdst, int n_off) {
  __shared__ unsigned short Ts[64][72];
  const int n0 = blockIdx.x * 64, k0 = blockIdx.y * 64;
  const int tid = threadIdx.x;
  const int c2 = (tid & 31) * 2, rb = tid >> 5;
#pragma unroll
  for (int p = 0; p < 8; ++p) {
    int r = rb + p * 8;
    float2 v = *(const float2*)&W[(size_t)(k0 + r) * Nsrc + n0 + c2];
    Ts[c2][r] = f2bf(v.x);
    Ts[c2 + 1][r] = f2bf(v.y);
  }
  __syncthreads();
  const int n = tid >> 2, kq = (tid & 3) * 16;
  ushort8 w0 = *(const ushort8*)&Ts[n][kq];
  ushort8 w1 = *(const ushort8*)&Ts[n][kq + 8];
  size_t base = (size_t)(n_off + n0 + n) * Kdst + k0 + kq;
  *(ushort8*)&Wt[base] = w0;
  *(ushort8*)&Wt[base + 8] = w1;
}

// ---------------------------------------------------------------------------
__global__ __launch_bounds__(256) void transpose_v(
    const unsigned short* __restrict__ KVb, unsigned short* __restrict__ Vt) {
  __shared__ unsigned short Ts[64][72];
  const int c0 = blockIdx.x * 64, s0 = blockIdx.y * 64;
  const int tid = threadIdx.x;
  const int sr = tid >> 2, cq = (tid & 3) * 16;
  ushort8 a = *(const ushort8*)&KVb[(size_t)(s0 + sr) * KVROW + 512 + c0 + cq];
  ushort8 b = *(const ushort8*)&KVb[(size_t)(s0 + sr) * KVROW + 512 + c0 + cq + 8];
#pragma unroll
  for (int j = 0; j < 8; ++j) { Ts[cq + j][sr] = a[j]; Ts[cq + 8 + j][sr] = b[j]; }
  __syncthreads();
  const int c = tid >> 2, sq = (tid & 3) * 16;
  ushort8 w0 = *(const ushort8*)&Ts[c][sq];
  ushort8 w1 = *(const ushort8*)&Ts[c][sq + 8];
  *(ushort8*)&Vt[(size_t)(c0 + c) * S_LEN + s0 + sq] = w0;
  *(ushort8*)&Vt[(size_t)(c0 + c) * S_LEN + s0 + sq + 8] = w1;
}

// ---------------------------------------------------------------------------
// MFMA GEMM (TN) v3 (unchanged from R13): BM=128, BN=64, BK=64,
// global_load_lds staging, LDS dbuf, one barrier/step, XOR-swizzled tiles.
// ---------------------------------------------------------------------------
template <bool CF>
__global__ __launch_bounds__(256) void gemm_tn(
    const unsigned short* __restrict__ A, const unsigned short* __restrict__ Bt,
    void* __restrict__ C1, void* __restrict__ C2,
    int M, int N, int K, int splitcol, int ld1, int ld2) {
  __shared__ unsigned short As[2][128 * 64];
  __shared__ unsigned short Bs[2][64 * 64];
  const int m0 = blockIdx.y * 128, n0 = blockIdx.x * 64;
  const int tid = threadIdx.x, wid = tid >> 6, lane = tid & 63;
  const int wr = wid >> 1, wc = wid & 1;
  const int lr = lane & 15, lg = lane >> 4;

  f32x4 acc[4][2];
#pragma unroll
  for (int m = 0; m < 4; ++m)
#pragma unroll
    for (int n = 0; n < 2; ++n) acc[m][n] = (f32x4){0.f, 0.f, 0.f, 0.f};

  const int srow = lane >> 3;
  const int scolb = (lane & 7) << 4;
  auto stage = [&](int k0, int b) {
#pragma unroll
    for (int j = 0; j < 4; ++j) {
      int row = wid * 32 + j * 8 + srow;
      int src = (scolb ^ ((row & 7) << 4)) >> 1;
      gl2lds16(A + (size_t)(m0 + row) * K + k0 + src,
               &As[b][(wid * 32 + j * 8) * 64]);
    }
#pragma unroll
    for (int j = 0; j < 2; ++j) {
      int row = wid * 16 + j * 8 + srow;
      int src = (scolb ^ ((row & 7) << 4)) >> 1;
      gl2lds16(Bt + (size_t)(n0 + row) * K + k0 + src,
               &Bs[b][(wid * 16 + j * 8) * 64]);
    }
  };

  stage(0, 0);
  int cur = 0;
  for (int k0 = 0; k0 < K; k0 += 64) {
    __syncthreads();
    if (k0 + 64 < K) stage(k0 + 64, cur ^ 1);
#pragma unroll
    for (int s = 0; s < 2; ++s) {
      short8 af[4], bfv[2];
#pragma unroll
      for (int m = 0; m < 4; ++m) {
        int row = wr * 64 + m * 16 + lr;
        int off = ((s * 64 + lg * 16) ^ ((row & 7) << 4)) >> 1;
        af[m] = *(const short8*)&As[cur][row * 64 + off];
      }
#pragma unroll
      for (int n = 0; n < 2; ++n) {
        int row = wc * 32 + n * 16 + lr;
        int off = ((s * 64 + lg * 16) ^ ((row & 7) << 4)) >> 1;
        bfv[n] = *(const short8*)&Bs[cur][row * 64 + off];
      }
#pragma unroll
      for (int m = 0; m < 4; ++m)
#pragma unroll
        for (int n = 0; n < 2; ++n)
          acc[m][n] = __builtin_amdgcn_mfma_f32_16x16x32_bf16(af[m], bfv[n], acc[m][n], 0, 0, 0);
    }
    cur ^= 1;
  }

#pragma unroll
  for (int m = 0; m < 4; ++m)
#pragma unroll
    for (int n = 0; n < 2; ++n)
#pragma unroll
      for (int r = 0; r < 4; ++r) {
        int row = m0 + wr * 64 + m * 16 + lg * 4 + r;
        int col = n0 + wc * 32 + n * 16 + lr;
        float v = acc[m][n][r];
        if (CF) ((float*)C1)[(size_t)row * ld1 + col] = v;
        else if (col < splitcol) ((unsigned short*)C1)[(size_t)row * ld1 + col] = f2bf(v);
        else ((unsigned short*)C2)[(size_t)row * ld2 + (col - splitcol)] = f2bf(v);
      }
}

// ---------------------------------------------------------------------------
__global__ void rope2(unsigned short* __restrict__ Q,
                      unsigned short* __restrict__ KV,
                      const int* __restrict__ pos) {
  int idx = blockIdx.x * blockDim.x + threadIdx.x;
  if (idx >= S_LEN * 64) return;
  int s = idx >> 6, j = idx & 63;
  float inv = exp2f(-0.2076205059304703f * (float)j);
  float ang = (float)pos[s] * inv;
  float sn, cs;
  __sincosf(ang, &sn, &cs);
  auto rot = [&](unsigned short* base) {
    unsigned* p = (unsigned*)base;
    unsigned v = *p;
    float x0 = bf2f((unsigned short)(v & 0xffff));
    float x1 = bf2f((unsigned short)(v >> 16));
    unsigned r = (unsigned)f2bf(x0 * cs - x1 * sn) |
                 ((unsigned)f2bf(x0 * sn + x1 * cs) << 16);
    *p = r;
  };
#pragma unroll
  for (int hh = 0; hh < NH; ++hh) rot(Q + (size_t)s * HIDDIM + hh * HD + 2 * j);
#pragma unroll
  for (int hh = 0; hh < NKV; ++hh) rot(KV + (size_t)s * KVROW + hh * HD + 2 * j);
}

// ---------------------------------------------------------------------------
__global__ void maskbits_kernel(const int* __restrict__ amask,
                                unsigned* __restrict__ mb) {
  int w = threadIdx.x;
  unsigned m = 0;
#pragma unroll
  for (int b = 0; b < 32; ++b) m |= (amask[w * 32 + b] != 0 ? 1u : 0u) << b;
  mb[w] = m;
}

// ---------------------------------------------------------------------------
// Flash attention v12: uniform-work chunked grid (as R12), but block = 4
// waves x 256 thr; wave = 1 head x 32 q-rows (two 16-row MFMA sets a/b
// sharing every K/V fragment -> 32 MFMA per wave-step on 16 ds_reads).
// Uniform fast-path skips mask VALU on interior tiles. Same K/V swizzled
// staging via global_load_lds, same partial/combine layout as R12.
// ---------------------------------------------------------------------------
__global__ __launch_bounds__(256) void attn_kernel(
    const unsigned short* __restrict__ Qb, const unsigned short* __restrict__ KVb,
    const unsigned short* __restrict__ VtG, const unsigned* __restrict__ mbits,
    unsigned short* __restrict__ Ob,
    unsigned short* __restrict__ Opart, float* __restrict__ Lpart, int nsplit) {
  const int x = (int)blockIdx.x;        // 0..255
  const int qt = 63 - (x >> 2);         // short chunks last
  const int c = x & 3;
  const int kvh = (int)blockIdx.y;
  const int nch = (qt >> 4) + 1;
  if (nsplit == 0) { if (c != 0) return; }
  else if (c >= nch) return;
  const int qb = qt * 32;
  int kbeg = 0, kend = qb + 32;
  bool partial = false;
  if (nsplit && nch > 1) {
    kbeg = c * 512;
    kend = min(kend, kbeg + 512);
    partial = true;
  }

  __shared__ unsigned short Klds[2][32 * 128];  // K[key][d], swizzled
  __shared__ unsigned short Vlds[2][128 * 32];  // V^T[d][key], swizzled
  __shared__ unsigned short Plds[4][32][40];    // per-wave P[q32][key]
  const int tid = threadIdx.x, wid = tid >> 6, lane = tid & 63;
  const int lr = lane & 15, lg = lane >> 4;
  const int h = kvh * 4 + wid;                  // wave's head

  short8 qfa[4], qfb[4];
  {
    const unsigned short* qpa = Qb + (size_t)(qb + lr) * HIDDIM + h * HD;
    const unsigned short* qpb = Qb + (size_t)(qb + 16 + lr) * HIDDIM + h * HD;
#pragma unroll
    for (int cc = 0; cc < 4; ++cc) {
      qfa[cc] = *(const short8*)(qpa + cc * 32 + lg * 8);
      qfb[cc] = *(const short8*)(qpb + cc * 32 + lg * 8);
    }
  }
  f32x4 oa[8], ob[8];
#pragma unroll
  for (int cc = 0; cc < 8; ++cc) {
    oa[cc] = (f32x4){0.f, 0.f, 0.f, 0.f};
    ob[cc] = (f32x4){0.f, 0.f, 0.f, 0.f};
  }
  float lsa = 0.f, lsb = 0.f;

  const unsigned short* Vg = VtG + (size_t)(kvh * HD) * S_LEN;

  // K stage: wave wid -> rows wid*8 + j*4 + (lane>>4); 256B rows.
  const int ksr_ = lane >> 4;
  const int kscb = (lane & 15) << 4;
  // V stage: wave wid -> rows wid*32 + j*16 + (lane>>2); 64B rows.
  const int vsr_ = lane >> 2;
  const int vscb = (lane & 3) << 4;

  auto stage = [&](int kt, int b) {
#pragma unroll
    for (int j = 0; j < 2; ++j) {
      int krow = wid * 8 + j * 4 + ksr_;
      int ksrc = (kscb ^ ((krow & 7) << 4)) >> 1;
      gl2lds16(KVb + (size_t)(kt + krow) * KVROW + kvh * HD + ksrc,
               &Klds[b][(wid * 8 + j * 4) * 128]);
      int vrow = wid * 32 + j * 16 + vsr_;
      int vsrc = (vscb ^ ((vrow & 3) << 4)) >> 1;
      gl2lds16(Vg + (size_t)vrow * S_LEN + kt + vsrc,
               &Vlds[b][(wid * 32 + j * 16) * 32]);
    }
  };

  stage(kbeg, 0);

  const int qra = qb + lr, qrb = qb + 16 + lr;
  const float SCALE = 0.08838834764831845f;
  int cur = 0;

  for (int kt = kbeg; kt < kend; kt += 32) {
    __syncthreads();  // drains async stage into buf[cur]
    if (kt + 32 < kend) stage(kt + 32, cur ^ 1);

    f32x4 sa[2], sb[2];
#pragma unroll
    for (int t = 0; t < 2; ++t) {
      sa[t] = (f32x4){0.f, 0.f, 0.f, 0.f};
      sb[t] = (f32x4){0.f, 0.f, 0.f, 0.f};
    }
    const unsigned short* kbase = &Klds[cur][0];
    __builtin_amdgcn_s_setprio(1);
#pragma unroll
    for (int t = 0; t < 2; ++t)
#pragma unroll
      for (int cc = 0; cc < 4; ++cc) {
        short8 kf = *(const short8*)(kbase + ((t * 16 + lr) << 7) +
                                     ((((cc << 6) + (lg << 4)) ^ ((lr & 7) << 4)) >> 1));
        sa[t] = __builtin_amdgcn_mfma_f32_16x16x32_bf16(kf, qfa[cc], sa[t], 0, 0, 0);
        sb[t] = __builtin_amdgcn_mfma_f32_16x16x32_bf16(kf, qfb[cc], sb[t], 0, 0, 0);
      }
    __builtin_amdgcn_s_setprio(0);
    const unsigned mw = mbits[kt >> 5];
    float pa[2][4], pb[2][4];
    if ((kt + 31 <= qb) && (mw == ~0u)) {
      // interior tile: no masking needed
#pragma unroll
      for (int t = 0; t < 2; ++t)
#pragma unroll
        for (int r = 0; r < 4; ++r) {
          float va = __expf(sa[t][r] * SCALE - 3.0f);
          float vb = __expf(sb[t][r] * SCALE - 3.0f);
          pa[t][r] = va; lsa += va;
          pb[t][r] = vb; lsb += vb;
        }
    } else {
#pragma unroll
      for (int t = 0; t < 2; ++t)
#pragma unroll
        for (int r = 0; r < 4; ++r) {
          int kk = t * 16 + lg * 4 + r;
          bool okm = (mw >> kk) & 1u;
          float va = __expf((okm && kt + kk <= qra) ? sa[t][r] * SCALE - 3.0f : -1e30f);
          float vb = __expf((okm && kt + kk <= qrb) ? sb[t][r] * SCALE - 3.0f : -1e30f);
          pa[t][r] = va; lsa += va;
          pb[t][r] = vb; lsb += vb;
        }
    }
#pragma unroll
    for (int t = 0; t < 2; ++t) {
      ushort4v pka, pkb;
#pragma unroll
      for (int r = 0; r < 4; ++r) { pka[r] = f2bf(pa[t][r]); pkb[r] = f2bf(pb[t][r]); }
      *(ushort4v*)&Plds[wid][lr][t * 16 + lg * 4] = pka;
      *(ushort4v*)&Plds[wid][16 + lr][t * 16 + lg * 4] = pkb;
    }
    short8 pfa = *(const short8*)&Plds[wid][lr][lg * 8];
    short8 pfb = *(const short8*)&Plds[wid][16 + lr][lg * 8];
    const unsigned short* vbase = &Vlds[cur][0];
    __builtin_amdgcn_s_setprio(1);
#pragma unroll
    for (int cc = 0; cc < 8; ++cc) {
      short8 vf = *(const short8*)(vbase + ((cc * 16 + lr) << 5) +
                                   ((lg ^ (lr & 3)) << 3));
      oa[cc] = __builtin_amdgcn_mfma_f32_16x16x32_bf16(pfa, vf, oa[cc], 0, 0, 0);
      ob[cc] = __builtin_amdgcn_mfma_f32_16x16x32_bf16(pfb, vf, ob[cc], 0, 0, 0);
    }
    __builtin_amdgcn_s_setprio(0);
    cur ^= 1;
  }

  float la = lsa;
  la += __shfl_xor(la, 16, 64);
  la += __shfl_xor(la, 32, 64);
  float lb = lsb;
  lb += __shfl_xor(lb, 16, 64);
  lb += __shfl_xor(lb, 32, 64);

  if (!partial) {
    float lra[4], lrb[4];
#pragma unroll
    for (int r = 0; r < 4; ++r) {
      lra[r] = 1.0f / __shfl(la, lg * 4 + r, 16);
      lrb[r] = 1.0f / __shfl(lb, lg * 4 + r, 16);
    }
#pragma unroll
    for (int cc = 0; cc < 8; ++cc)
#pragma unroll
      for (int r = 0; r < 4; ++r) {
        const int rowa = qb + lg * 4 + r;
        const int rowb = qb + 16 + lg * 4 + r;
        Ob[(size_t)rowa * HIDDIM + h * HD + cc * 16 + lr] = f2bf(oa[cc][r] * lra[r]);
        Ob[(size_t)rowb * HIDDIM + h * HD + cc * 16 + lr] = f2bf(ob[cc][r] * lrb[r]);
      }
  } else {
    const int g = qt >> 4, j = qt & 15;
    const int base = (g == 1) ? 0 : (g == 2) ? 32 : 80;
    const int slot = base + j * nch + c + 144 * kvh;
    if (lg == 0) {
      Lpart[slot * 128 + wid * 32 + lr] = la;
      Lpart[slot * 128 + wid * 32 + 16 + lr] = lb;
    }
#pragma unroll
    for (int cc = 0; cc < 8; ++cc)
#pragma unroll
      for (int r = 0; r < 4; ++r) {
        Opart[(size_t)slot * 16384 + wid * 4096 +
              (lg * 4 + r) * 128 + cc * 16 + lr] = f2bf(oa[cc][r]);
        Opart[(size_t)slot * 16384 + wid * 4096 +
              (16 + lg * 4 + r) * 128 + cc * 16 + lr] = f2bf(ob[cc][r]);
      }
  }
}

// ---------------------------------------------------------------------------
__global__ __launch_bounds__(256) void combine_kernel(
    const unsigned short* __restrict__ Opart, const float* __restrict__ Lpart,
    unsigned short* __restrict__ Ab) {
  const int qt = 16 + (int)blockIdx.x;
  const int kvh = (int)blockIdx.y;
  const int nch = (qt >> 4) + 1;
  const int g = qt >> 4, j = qt & 15;
  const int base = (g == 1) ? 0 : (g == 2) ? 32 : 80;
  const int s0 = base + j * nch + 144 * kvh;
  const int tid = threadIdx.x;
  const int rowid = tid >> 1;
  const int d0 = (tid & 1) * 64;
  float L = 0.f;
  for (int cc = 0; cc < nch; ++cc) L += Lpart[(s0 + cc) * 128 + rowid];
  const float linv = 1.0f / L;
  const int h = kvh * 4 + (rowid >> 5);
  const int row = qt * 32 + (rowid & 31);
  unsigned short* dst = Ab + (size_t)row * HIDDIM + h * HD + d0;
  for (int i = 0; i < 64; i += 8) {
    float acc[8] = {0, 0, 0, 0, 0, 0, 0, 0};
    for (int cc = 0; cc < nch; ++cc) {
      ushort8 v = *(const ushort8*)&Opart[(size_t)(s0 + cc) * 16384 +
                                          rowid * 128 + d0 + i];
#pragma unroll
      for (int k = 0; k < 8; ++k) acc[k] += bf2f(v[k]);
    }
    ushort8 r;
#pragma unroll
    for (int k = 0; k < 8; ++k) r[k] = f2bf(acc[k] * linv);
    *(ushort8*)(dst + i) = r;
  }
}

// ---------------------------------------------------------------------------
extern "C" void kernel_launch(void* const* d_in, const int* in_sizes, int n_in,
                              void* d_out, int out_size, void* d_ws, size_t ws_size,
                              hipStream_t stream) {
  const float* hidden = (const float*)d_in[0];
  const float* wq = (const float*)d_in[1];
  const float* wk = (const float*)d_in[2];
  const float* wv = (const float*)d_in[3];
  const float* wo = (const float*)d_in[4];
  const int* amask = (const int*)d_in[5];
  const int* pos = (const int*)d_in[6];

  unsigned short* Qb = (unsigned short*)d_ws;              // 0      .. 8.39MB
  unsigned short* KVb = Qb + (size_t)S_LEN * HIDDIM;       // 8.39   .. 12.58
  unsigned short* Ab = KVb + (size_t)S_LEN * KVROW;        // 12.58  .. 20.97
  unsigned short* WT1 = Ab + (size_t)S_LEN * HIDDIM;       // 20.97  .. 33.55
  unsigned short* Hb = WT1 + (size_t)QKVN * HIDDIM;        // 33.55  .. 41.94
  float* out = (float*)d_out;

  // Chunked-path extras (aliasing WT1+Hb, dead during attn):
  unsigned short* Opart = WT1;                             // 576 slots x 32KB
  unsigned short* Vt_chunk = WT1 + (size_t)576 * 16384;
  unsigned* mbits_chunk = (unsigned*)((char*)d_ws + 41943040ull);
  float* Lpart = (float*)((char*)d_ws + 41943296ull);
  const size_t need_chunk = 42238208ull;
  // Fallback locations:
  unsigned short* Vt_fb = WT1 + (size_t)HIDDIM * HIDDIM;
  unsigned* mbits_fb = (unsigned*)((char*)d_ws + 31457280ull);

  const int nsplit = (ws_size >= need_chunk) ? 1 : 0;
  unsigned short* Vt = nsplit ? Vt_chunk : Vt_fb;
  unsigned* mbits = nsplit ? mbits_chunk : mbits_fb;

  dim3 blk(256);
  h2b_kernel<<<2048, blk, 0, stream>>>(hidden, Hb);
  transpose_w<<<dim3(32, 32), blk, 0, stream>>>(wq, WT1, HIDDIM, HIDDIM, 0);
  transpose_w<<<dim3(8, 32), blk, 0, stream>>>(wk, WT1, 512, HIDDIM, 2048);
  transpose_w<<<dim3(8, 32), blk, 0, stream>>>(wv, WT1, 512, HIDDIM, 2560);
  // Fused QKV projection: cols<2048 -> Qb, else -> KVb
  gemm_tn<false><<<dim3(QKVN / 64, S_LEN / 128), blk, 0, stream>>>(
      Hb, WT1, Qb, KVb, S_LEN, QKVN, HIDDIM, 2048, HIDDIM, KVROW);
  // V transpose (V not rope'd)
  transpose_v<<<dim3(8, 32), blk, 0, stream>>>(KVb, Vt);
  rope2<<<(S_LEN * 64 + 255) / 256, blk, 0, stream>>>(Qb, KVb, pos);
  maskbits_kernel<<<1, 64, 0, stream>>>(amask, mbits);
  // Attention: uniform-work chunked grid, 4-wave blocks
  attn_kernel<<<dim3(256, NKV), blk, 0, stream>>>(
      Qb, KVb, Vt, mbits, Ab, Opart, Lpart, nsplit);
  if (nsplit)
    combine_kernel<<<dim3(48, NKV), blk, 0, stream>>>(Opart, Lpart, Ab);
  // Wo^T AFTER attn/combine (it overwrites the Opart region)
  transpose_w<<<dim3(32, 32), blk, 0, stream>>>(wo, WT1, HIDDIM, HIDDIM, 0);
  // Output projection (fp32 out)
  gemm_tn<true><<<dim3(HIDDIM / 64, S_LEN / 128), blk, 0, stream>>>(
      Ab, WT1, out, nullptr, S_LEN, HIDDIM, HIDDIM, HIDDIM, HIDDIM, 0);
}

// Round 15
// 162.322 us; speedup vs baseline: 1.2311x; 1.0506x over previous
//
#include <hip/hip_runtime.h>
#include <hip/hip_bf16.h>

// Shapes (fixed for this problem)
#define S_LEN 2048
#define HIDDIM 2048
#define NH 16
#define NKV 4
#define HD 128
#define KVROW 1024   // KVb row = [K(512) | V(512)]
#define QKVN 3072    // fused projection width

typedef __attribute__((ext_vector_type(8))) short short8;
typedef __attribute__((ext_vector_type(8))) unsigned short ushort8;
typedef __attribute__((ext_vector_type(4))) float f32x4;

__device__ __forceinline__ unsigned short f2bf(float f) {
  union { float f; unsigned int u; } v; v.f = f;
  unsigned int r = (v.u + 0x7FFFu + ((v.u >> 16) & 1u)) >> 16;
  return (unsigned short)r;
}
__device__ __forceinline__ float bf2f(unsigned short h) {
  union { unsigned int u; float f; } v; v.u = ((unsigned int)h) << 16;
  return v.f;
}

// Async global->LDS 16B copy. dst wave-uniform (HW adds lane*16B); src per-lane.
__device__ __forceinline__ void gl2lds16(const unsigned short* src,
                                         unsigned short* dst) {
  __builtin_amdgcn_global_load_lds(
      (const __attribute__((address_space(1))) unsigned int*)src,
      (__attribute__((address_space(3))) unsigned int*)dst, 16, 0, 0);
}

// ---------------------------------------------------------------------------
// Weight transpose body: W[k][n] fp32 (stride Nsrc) -> Wt[n_off+n][k] bf16.
// ---------------------------------------------------------------------------
__device__ __forceinline__ void tw_body(
    const float* __restrict__ W, unsigned short* __restrict__ Wt,
    int Nsrc, int Kdst, int n_off, int bx, int by, int tid,
    unsigned short (*Ts)[72]) {
  const int n0 = bx * 64, k0 = by * 64;
  const int c2 = (tid & 31) * 2, rb = tid >> 5;
#pragma unroll
  for (int p = 0; p < 8; ++p) {
    int r = rb + p * 8;
    float2 v = *(const float2*)&W[(size_t)(k0 + r) * Nsrc + n0 + c2];
    Ts[c2][r] = f2bf(v.x);
    Ts[c2 + 1][r] = f2bf(v.y);
  }
  __syncthreads();
  const int n = tid >> 2, kq = (tid & 3) * 16;
  ushort8 w0 = *(const ushort8*)&Ts[n][kq];
  ushort8 w1 = *(const ushort8*)&Ts[n][kq + 8];
  size_t base = (size_t)(n_off + n0 + n) * Kdst + k0 + kq;
  *(ushort8*)&Wt[base] = w0;
  *(ushort8*)&Wt[base + 8] = w1;
}

// ---------------------------------------------------------------------------
// Fused prep: h2b (blocks 0..2047) + wq^T (2048..3071) + wk^T (3072..3327)
// + wv^T (3328..3583) + maskbits (3584).
// ---------------------------------------------------------------------------
__global__ __launch_bounds__(256) void prep_kernel(
    const float* __restrict__ H, unsigned short* __restrict__ Hb,
    const float* __restrict__ wq, const float* __restrict__ wk,
    const float* __restrict__ wv, unsigned short* __restrict__ WT1,
    const int* __restrict__ amask, unsigned* __restrict__ mb) {
  __shared__ unsigned short Ts[64][72];
  const int b = (int)blockIdx.x, tid = threadIdx.x;
  if (b < 2048) {
    int i = (b * 256 + tid) * 8;
    float4 a = *(const float4*)(H + i), c = *(const float4*)(H + i + 4);
    ushort8 r;
    r[0] = f2bf(a.x); r[1] = f2bf(a.y); r[2] = f2bf(a.z); r[3] = f2bf(a.w);
    r[4] = f2bf(c.x); r[5] = f2bf(c.y); r[6] = f2bf(c.z); r[7] = f2bf(c.w);
    *(ushort8*)(Hb + i) = r;
  } else if (b < 3072) {
    int t = b - 2048;
    tw_body(wq, WT1, HIDDIM, HIDDIM, 0, t & 31, t >> 5, tid, Ts);
  } else if (b < 3328) {
    int t = b - 3072;
    tw_body(wk, WT1, 512, HIDDIM, 2048, t & 7, t >> 3, tid, Ts);
  } else if (b < 3584) {
    int t = b - 3328;
    tw_body(wv, WT1, 512, HIDDIM, 2560, t & 7, t >> 3, tid, Ts);
  } else {
    if (tid < 64) {
      unsigned m = 0;
#pragma unroll
      for (int i = 0; i < 32; ++i) m |= (amask[tid * 32 + i] != 0 ? 1u : 0u) << i;
      mb[tid] = m;
    }
  }
}

// ---------------------------------------------------------------------------
// Standalone weight transpose (Wo^T, runs after attn).
// ---------------------------------------------------------------------------
__global__ __launch_bounds__(256) void transpose_w(
    const float* __restrict__ W, unsigned short* __restrict__ Wt,
    int Nsrc, int Kdst, int n_off) {
  __shared__ unsigned short Ts[64][72];
  tw_body(W, Wt, Nsrc, Kdst, n_off, (int)blockIdx.x, (int)blockIdx.y,
          (int)threadIdx.x, Ts);
}

// ---------------------------------------------------------------------------
// Fused transpose_v (blocks 0..255) + rope (256..767).
// ---------------------------------------------------------------------------
__global__ __launch_bounds__(256) void tvrope_kernel(
    unsigned short* __restrict__ Qb, unsigned short* __restrict__ KVb,
    unsigned short* __restrict__ Vt, const int* __restrict__ pos) {
  __shared__ unsigned short Ts[64][72];
  const int b = (int)blockIdx.x, tid = threadIdx.x;
  if (b < 256) {
    const int c0 = (b & 7) * 64, s0 = (b >> 3) * 64;
    const int sr = tid >> 2, cq = (tid & 3) * 16;
    ushort8 a = *(const ushort8*)&KVb[(size_t)(s0 + sr) * KVROW + 512 + c0 + cq];
    ushort8 c = *(const ushort8*)&KVb[(size_t)(s0 + sr) * KVROW + 512 + c0 + cq + 8];
#pragma unroll
    for (int j = 0; j < 8; ++j) { Ts[cq + j][sr] = a[j]; Ts[cq + 8 + j][sr] = c[j]; }
    __syncthreads();
    const int cc = tid >> 2, sq = (tid & 3) * 16;
    ushort8 w0 = *(const ushort8*)&Ts[cc][sq];
    ushort8 w1 = *(const ushort8*)&Ts[cc][sq + 8];
    *(ushort8*)&Vt[(size_t)(c0 + cc) * S_LEN + s0 + sq] = w0;
    *(ushort8*)&Vt[(size_t)(c0 + cc) * S_LEN + s0 + sq + 8] = w1;
  } else {
    int idx = (b - 256) * 256 + tid;
    int s = idx >> 6, j = idx & 63;
    float inv = exp2f(-0.2076205059304703f * (float)j);
    float ang = (float)pos[s] * inv;
    float sn, cs;
    __sincosf(ang, &sn, &cs);
    auto rot = [&](unsigned short* base) {
      unsigned* p = (unsigned*)base;
      unsigned v = *p;
      float x0 = bf2f((unsigned short)(v & 0xffff));
      float x1 = bf2f((unsigned short)(v >> 16));
      unsigned r = (unsigned)f2bf(x0 * cs - x1 * sn) |
                   ((unsigned)f2bf(x0 * sn + x1 * cs) << 16);
      *p = r;
    };
#pragma unroll
    for (int hh = 0; hh < NH; ++hh) rot(Qb + (size_t)s * HIDDIM + hh * HD + 2 * j);
#pragma unroll
    for (int hh = 0; hh < NKV; ++hh) rot(KVb + (size_t)s * KVROW + hh * HD + 2 * j);
  }
}

// ---------------------------------------------------------------------------
// MFMA GEMM (TN) v3 (unchanged from R13): BM=128, BN=64, BK=64,
// global_load_lds staging, LDS dbuf, one barrier/step, XOR-swizzled tiles.
// ---------------------------------------------------------------------------
template <bool CF>
__global__ __launch_bounds__(256) void gemm_tn(
    const unsigned short* __restrict__ A, const unsigned short* __restrict__ Bt,
    void* __restrict__ C1, void* __restrict__ C2,
    int M, int N, int K, int splitcol, int ld1, int ld2) {
  __shared__ unsigned short As[2][128 * 64];
  __shared__ unsigned short Bs[2][64 * 64];
  const int m0 = blockIdx.y * 128, n0 = blockIdx.x * 64;
  const int tid = threadIdx.x, wid = tid >> 6, lane = tid & 63;
  const int wr = wid >> 1, wc = wid & 1;
  const int lr = lane & 15, lg = lane >> 4;

  f32x4 acc[4][2];
#pragma unroll
  for (int m = 0; m < 4; ++m)
#pragma unroll
    for (int n = 0; n < 2; ++n) acc[m][n] = (f32x4){0.f, 0.f, 0.f, 0.f};

  const int srow = lane >> 3;
  const int scolb = (lane & 7) << 4;
  auto stage = [&](int k0, int b) {
#pragma unroll
    for (int j = 0; j < 4; ++j) {
      int row = wid * 32 + j * 8 + srow;
      int src = (scolb ^ ((row & 7) << 4)) >> 1;
      gl2lds16(A + (size_t)(m0 + row) * K + k0 + src,
               &As[b][(wid * 32 + j * 8) * 64]);
    }
#pragma unroll
    for (int j = 0; j < 2; ++j) {
      int row = wid * 16 + j * 8 + srow;
      int src = (scolb ^ ((row & 7) << 4)) >> 1;
      gl2lds16(Bt + (size_t)(n0 + row) * K + k0 + src,
               &Bs[b][(wid * 16 + j * 8) * 64]);
    }
  };

  stage(0, 0);
  int cur = 0;
  for (int k0 = 0; k0 < K; k0 += 64) {
    __syncthreads();
    if (k0 + 64 < K) stage(k0 + 64, cur ^ 1);
#pragma unroll
    for (int s = 0; s < 2; ++s) {
      short8 af[4], bfv[2];
#pragma unroll
      for (int m = 0; m < 4; ++m) {
        int row = wr * 64 + m * 16 + lr;
        int off = ((s * 64 + lg * 16) ^ ((row & 7) << 4)) >> 1;
        af[m] = *(const short8*)&As[cur][row * 64 + off];
      }
#pragma unroll
      for (int n = 0; n < 2; ++n) {
        int row = wc * 32 + n * 16 + lr;
        int off = ((s * 64 + lg * 16) ^ ((row & 7) << 4)) >> 1;
        bfv[n] = *(const short8*)&Bs[cur][row * 64 + off];
      }
#pragma unroll
      for (int m = 0; m < 4; ++m)
#pragma unroll
        for (int n = 0; n < 2; ++n)
          acc[m][n] = __builtin_amdgcn_mfma_f32_16x16x32_bf16(af[m], bfv[n], acc[m][n], 0, 0, 0);
    }
    cur ^= 1;
  }

#pragma unroll
  for (int m = 0; m < 4; ++m)
#pragma unroll
    for (int n = 0; n < 2; ++n)
#pragma unroll
      for (int r = 0; r < 4; ++r) {
        int row = m0 + wr * 64 + m * 16 + lg * 4 + r;
        int col = n0 + wc * 32 + n * 16 + lr;
        float v = acc[m][n][r];
        if (CF) ((float*)C1)[(size_t)row * ld1 + col] = v;
        else if (col < splitcol) ((unsigned short*)C1)[(size_t)row * ld1 + col] = f2bf(v);
        else ((unsigned short*)C2)[(size_t)row * ld2 + (col - splitcol)] = f2bf(v);
      }
}

// ---------------------------------------------------------------------------
// Flash attention v13: R14 structure (4 waves, wave = head x 32 q-rows, two
// 16-row sets sharing K/V frags, uniform-work chunked grid) but with LDS cut
// to EXACTLY 32KB: no Plds -- P routed to A-frag layout in-register via
// 8 bpermutes/set (R5-verified index algebra). K/V dbuf via global_load_lds,
// swizzled. Occupancy experiment: 43KB -> 32KB.
// ---------------------------------------------------------------------------
__global__ __launch_bounds__(256) void attn_kernel(
    const unsigned short* __restrict__ Qb, const unsigned short* __restrict__ KVb,
    const unsigned short* __restrict__ VtG, const unsigned* __restrict__ mbits,
    unsigned short* __restrict__ Ob,
    unsigned short* __restrict__ Opart, float* __restrict__ Lpart, int nsplit) {
  const int x = (int)blockIdx.x;        // 0..255
  const int qt = 63 - (x >> 2);         // short chunks last
  const int c = x & 3;
  const int kvh = (int)blockIdx.y;
  const int nch = (qt >> 4) + 1;
  if (nsplit == 0) { if (c != 0) return; }
  else if (c >= nch) return;
  const int qb = qt * 32;
  int kbeg = 0, kend = qb + 32;
  bool partial = false;
  if (nsplit && nch > 1) {
    kbeg = c * 512;
    kend = min(kend, kbeg + 512);
    partial = true;
  }

  __shared__ unsigned short Klds[2][32 * 128];  // K[key][d], swizzled (16KB)
  __shared__ unsigned short Vlds[2][128 * 32];  // V^T[d][key], swizzled (16KB)
  const int tid = threadIdx.x, wid = tid >> 6, lane = tid & 63;
  const int lr = lane & 15, lg = lane >> 4;
  const int h = kvh * 4 + wid;                  // wave's head

  short8 qfa[4], qfb[4];
  {
    const unsigned short* qpa = Qb + (size_t)(qb + lr) * HIDDIM + h * HD;
    const unsigned short* qpb = Qb + (size_t)(qb + 16 + lr) * HIDDIM + h * HD;
#pragma unroll
    for (int cc = 0; cc < 4; ++cc) {
      qfa[cc] = *(const short8*)(qpa + cc * 32 + lg * 8);
      qfb[cc] = *(const short8*)(qpb + cc * 32 + lg * 8);
    }
  }
  f32x4 oa[8], ob[8];
#pragma unroll
  for (int cc = 0; cc < 8; ++cc) {
    oa[cc] = (f32x4){0.f, 0.f, 0.f, 0.f};
    ob[cc] = (f32x4){0.f, 0.f, 0.f, 0.f};
  }
  float lsa = 0.f, lsb = 0.f;

  const unsigned short* Vg = VtG + (size_t)(kvh * HD) * S_LEN;

  const int ksr_ = lane >> 4;
  const int kscb = (lane & 15) << 4;
  const int vsr_ = lane >> 2;
  const int vscb = (lane & 3) << 4;

  auto stage = [&](int kt, int b) {
#pragma unroll
    for (int j = 0; j < 2; ++j) {
      int krow = wid * 8 + j * 4 + ksr_;
      int ksrc = (kscb ^ ((krow & 7) << 4)) >> 1;
      gl2lds16(KVb + (size_t)(kt + krow) * KVROW + kvh * HD + ksrc,
               &Klds[b][(wid * 8 + j * 4) * 128]);
      int vrow = wid * 32 + j * 16 + vsr_;
      int vsrc = (vscb ^ ((vrow & 3) << 4)) >> 1;
      gl2lds16(Vg + (size_t)vrow * S_LEN + kt + vsrc,
               &Vlds[b][(wid * 32 + j * 16) * 32]);
    }
  };

  stage(kbeg, 0);

  const int qra = qb + lr, qrb = qb + 16 + lr;
  const float SCALE = 0.08838834764831845f;
  int cur = 0;

  // In-register P exchange: lane (lr,lg) needs keys 8lg..8lg+7 held as
  // {W0,W1 | W2,W3} by lanes s0 = lr+32*(lg&1) and s1 = s0+16 (t-half by lg<2).
  const int s0 = lr + ((lg & 1) << 5);
  const int s1 = s0 + 16;
  const bool lo = (lg < 2);
  auto exchange = [&](const float p[2][4]) -> short8 {
    unsigned W0 = (unsigned)f2bf(p[0][0]) | ((unsigned)f2bf(p[0][1]) << 16);
    unsigned W1 = (unsigned)f2bf(p[0][2]) | ((unsigned)f2bf(p[0][3]) << 16);
    unsigned W2 = (unsigned)f2bf(p[1][0]) | ((unsigned)f2bf(p[1][1]) << 16);
    unsigned W3 = (unsigned)f2bf(p[1][2]) | ((unsigned)f2bf(p[1][3]) << 16);
    unsigned x0 = __shfl(W0, s0, 64), y0 = __shfl(W2, s0, 64);
    unsigned x1 = __shfl(W1, s0, 64), y1 = __shfl(W3, s0, 64);
    unsigned x2 = __shfl(W0, s1, 64), y2 = __shfl(W2, s1, 64);
    unsigned x3 = __shfl(W1, s1, 64), y3 = __shfl(W3, s1, 64);
    union { unsigned u[4]; short8 s8; } pu;
    pu.u[0] = lo ? x0 : y0;
    pu.u[1] = lo ? x1 : y1;
    pu.u[2] = lo ? x2 : y2;
    pu.u[3] = lo ? x3 : y3;
    return pu.s8;
  };

  for (int kt = kbeg; kt < kend; kt += 32) {
    __syncthreads();  // drains async stage into buf[cur]
    if (kt + 32 < kend) stage(kt + 32, cur ^ 1);

    f32x4 sa[2], sb[2];
#pragma unroll
    for (int t = 0; t < 2; ++t) {
      sa[t] = (f32x4){0.f, 0.f, 0.f, 0.f};
      sb[t] = (f32x4){0.f, 0.f, 0.f, 0.f};
    }
    const unsigned short* kbase = &Klds[cur][0];
    __builtin_amdgcn_s_setprio(1);
#pragma unroll
    for (int t = 0; t < 2; ++t)
#pragma unroll
      for (int cc = 0; cc < 4; ++cc) {
        short8 kf = *(const short8*)(kbase + ((t * 16 + lr) << 7) +
                                     ((((cc << 6) + (lg << 4)) ^ ((lr & 7) << 4)) >> 1));
        sa[t] = __builtin_amdgcn_mfma_f32_16x16x32_bf16(kf, qfa[cc], sa[t], 0, 0, 0);
        sb[t] = __builtin_amdgcn_mfma_f32_16x16x32_bf16(kf, qfb[cc], sb[t], 0, 0, 0);
      }
    __builtin_amdgcn_s_setprio(0);
    const unsigned mw = mbits[kt >> 5];
    float pa[2][4], pb[2][4];
    if ((kt + 31 <= qb) && (mw == ~0u)) {
#pragma unroll
      for (int t = 0; t < 2; ++t)
#pragma unroll
        for (int r = 0; r < 4; ++r) {
          float va = __expf(sa[t][r] * SCALE - 3.0f);
          float vb = __expf(sb[t][r] * SCALE - 3.0f);
          pa[t][r] = va; lsa += va;
          pb[t][r] = vb; lsb += vb;
        }
    } else {
#pragma unroll
      for (int t = 0; t < 2; ++t)
#pragma unroll
        for (int r = 0; r < 4; ++r) {
          int kk = t * 16 + lg * 4 + r;
          bool okm = (mw >> kk) & 1u;
          float va = __expf((okm && kt + kk <= qra) ? sa[t][r] * SCALE - 3.0f : -1e30f);
          float vb = __expf((okm && kt + kk <= qrb) ? sb[t][r] * SCALE - 3.0f : -1e30f);
          pa[t][r] = va; lsa += va;
          pb[t][r] = vb; lsb += vb;
        }
    }
    short8 pfa = exchange(pa);
    short8 pfb = exchange(pb);
    const unsigned short* vbase = &Vlds[cur][0];
    __builtin_amdgcn_s_setprio(1);
#pragma unroll
    for (int cc = 0; cc < 8; ++cc) {
      short8 vf = *(const short8*)(vbase + ((cc * 16 + lr) << 5) +
                                   ((lg ^ (lr & 3)) << 3));
      oa[cc] = __builtin_amdgcn_mfma_f32_16x16x32_bf16(pfa, vf, oa[cc], 0, 0, 0);
      ob[cc] = __builtin_amdgcn_mfma_f32_16x16x32_bf16(pfb, vf, ob[cc], 0, 0, 0);
    }
    __builtin_amdgcn_s_setprio(0);
    cur ^= 1;
  }

  float la = lsa;
  la += __shfl_xor(la, 16, 64);
  la += __shfl_xor(la, 32, 64);
  float lb = lsb;
  lb += __shfl_xor(lb, 16, 64);
  lb += __shfl_xor(lb, 32, 64);

  if (!partial) {
    float lra[4], lrb[4];
#pragma unroll
    for (int r = 0; r < 4; ++r) {
      lra[r] = 1.0f / __shfl(la, lg * 4 + r, 16);
      lrb[r] = 1.0f / __shfl(lb, lg * 4 + r, 16);
    }
#pragma unroll
    for (int cc = 0; cc < 8; ++cc)
#pragma unroll
      for (int r = 0; r < 4; ++r) {
        const int rowa = qb + lg * 4 + r;
        const int rowb = qb + 16 + lg * 4 + r;
        Ob[(size_t)rowa * HIDDIM + h * HD + cc * 16 + lr] = f2bf(oa[cc][r] * lra[r]);
        Ob[(size_t)rowb * HIDDIM + h * HD + cc * 16 + lr] = f2bf(ob[cc][r] * lrb[r]);
      }
  } else {
    const int g = qt >> 4, j = qt & 15;
    const int base = (g == 1) ? 0 : (g == 2) ? 32 : 80;
    const int slot = base + j * nch + c + 144 * kvh;
    if (lg == 0) {
      Lpart[slot * 128 + wid * 32 + lr] = la;
      Lpart[slot * 128 + wid * 32 + 16 + lr] = lb;
    }
#pragma unroll
    for (int cc = 0; cc < 8; ++cc)
#pragma unroll
      for (int r = 0; r < 4; ++r) {
        Opart[(size_t)slot * 16384 + wid * 4096 +
              (lg * 4 + r) * 128 + cc * 16 + lr] = f2bf(oa[cc][r]);
        Opart[(size_t)slot * 16384 + wid * 4096 +
              (16 + lg * 4 + r) * 128 + cc * 16 + lr] = f2bf(ob[cc][r]);
      }
  }
}

// ---------------------------------------------------------------------------
__global__ __launch_bounds__(256) void combine_kernel(
    const unsigned short* __restrict__ Opart, const float* __restrict__ Lpart,
    unsigned short* __restrict__ Ab) {
  const int qt = 16 + (int)blockIdx.x;
  const int kvh = (int)blockIdx.y;
  const int nch = (qt >> 4) + 1;
  const int g = qt >> 4, j = qt & 15;
  const int base = (g == 1) ? 0 : (g == 2) ? 32 : 80;
  const int s0 = base + j * nch + 144 * kvh;
  const int tid = threadIdx.x;
  const int rowid = tid >> 1;
  const int d0 = (tid & 1) * 64;
  float L = 0.f;
  for (int cc = 0; cc < nch; ++cc) L += Lpart[(s0 + cc) * 128 + rowid];
  const float linv = 1.0f / L;
  const int h = kvh * 4 + (rowid >> 5);
  const int row = qt * 32 + (rowid & 31);
  unsigned short* dst = Ab + (size_t)row * HIDDIM + h * HD + d0;
  for (int i = 0; i < 64; i += 8) {
    float acc[8] = {0, 0, 0, 0, 0, 0, 0, 0};
    for (int cc = 0; cc < nch; ++cc) {
      ushort8 v = *(const ushort8*)&Opart[(size_t)(s0 + cc) * 16384 +
                                          rowid * 128 + d0 + i];
#pragma unroll
      for (int k = 0; k < 8; ++k) acc[k] += bf2f(v[k]);
    }
    ushort8 r;
#pragma unroll
    for (int k = 0; k < 8; ++k) r[k] = f2bf(acc[k] * linv);
    *(ushort8*)(dst + i) = r;
  }
}

// ---------------------------------------------------------------------------
extern "C" void kernel_launch(void* const* d_in, const int* in_sizes, int n_in,
                              void* d_out, int out_size, void* d_ws, size_t ws_size,
                              hipStream_t stream) {
  const float* hidden = (const float*)d_in[0];
  const float* wq = (const float*)d_in[1];
  const float* wk = (const float*)d_in[2];
  const float* wv = (const float*)d_in[3];
  const float* wo = (const float*)d_in[4];
  const int* amask = (const int*)d_in[5];
  const int* pos = (const int*)d_in[6];

  unsigned short* Qb = (unsigned short*)d_ws;              // 0      .. 8.39MB
  unsigned short* KVb = Qb + (size_t)S_LEN * HIDDIM;       // 8.39   .. 12.58
  unsigned short* Ab = KVb + (size_t)S_LEN * KVROW;        // 12.58  .. 20.97
  unsigned short* WT1 = Ab + (size_t)S_LEN * HIDDIM;       // 20.97  .. 33.55
  unsigned short* Hb = WT1 + (size_t)QKVN * HIDDIM;        // 33.55  .. 41.94
  float* out = (float*)d_out;

  // Chunked-path extras (aliasing WT1+Hb, dead during attn):
  unsigned short* Opart = WT1;                             // 576 slots x 32KB
  unsigned short* Vt_chunk = WT1 + (size_t)576 * 16384;
  unsigned* mbits_chunk = (unsigned*)((char*)d_ws + 41943040ull);
  float* Lpart = (float*)((char*)d_ws + 41943296ull);
  const size_t need_chunk = 42238208ull;
  // Fallback locations:
  unsigned short* Vt_fb = WT1 + (size_t)HIDDIM * HIDDIM;
  unsigned* mbits_fb = (unsigned*)((char*)d_ws + 31457280ull);

  const int nsplit = (ws_size >= need_chunk) ? 1 : 0;
  unsigned short* Vt = nsplit ? Vt_chunk : Vt_fb;
  unsigned* mbits = nsplit ? mbits_chunk : mbits_fb;

  dim3 blk(256);
  // Fused prep: h2b + wq/wk/wv transposes + maskbits
  prep_kernel<<<3585, blk, 0, stream>>>(hidden, Hb, wq, wk, wv, WT1, amask, mbits);
  // Fused QKV projection: cols<2048 -> Qb, else -> KVb
  gemm_tn<false><<<dim3(QKVN / 64, S_LEN / 128), blk, 0, stream>>>(
      Hb, WT1, Qb, KVb, S_LEN, QKVN, HIDDIM, 2048, HIDDIM, KVROW);
  // Fused V transpose + RoPE
  tvrope_kernel<<<768, blk, 0, stream>>>(Qb, KVb, Vt, pos);
  // Attention: uniform-work chunked grid, 4-wave blocks, 32KB LDS
  attn_kernel<<<dim3(256, NKV), blk, 0, stream>>>(
      Qb, KVb, Vt, mbits, Ab, Opart, Lpart, nsplit);
  if (nsplit)
    combine_kernel<<<dim3(48, NKV), blk, 0, stream>>>(Opart, Lpart, Ab);
  // Wo^T AFTER attn/combine (it overwrites the Opart region)
  transpose_w<<<dim3(32, 32), blk, 0, stream>>>(wo, WT1, HIDDIM, HIDDIM, 0);
  // Output projection (fp32 out)
  gemm_tn<true><<<dim3(HIDDIM / 64, S_LEN / 128), blk, 0, stream>>>(
      Ab, WT1, out, nullptr, S_LEN, HIDDIM, HIDDIM, HIDDIM, HIDDIM, 0);
}